// Round 2
// baseline (452.774 us; speedup 1.0000x reference)
//
#include <hip/hip_runtime.h>
#include <math.h>

// ---------------------------------------------------------------------------
// SelfAttention (DiT block): adaLN -> LN -> qkv GEMM -> RoPE -> block-masked
// attention -> out GEMM + skip.  B=8, S=1365, DIM=1024, H=16, D=64.
// R5: GEMMs on BM=BN=128/BK=64, 256-thread (4-wave) counted-vmcnt pipeline,
// 64 KiB LDS -> 2 blocks/CU (restores cross-block latency hiding, the m114
// mechanism), T2 swizzle kept (conflicts were 0 in R4), supertiled XCD-aware
// block order for L2 locality.  gemm_out gets the same template (fixes its
// 228-block under-occupancy).
// ---------------------------------------------------------------------------

typedef unsigned short u16;
typedef unsigned short u16x8 __attribute__((ext_vector_type(8)));
typedef unsigned short u16x4 __attribute__((ext_vector_type(4)));
typedef __bf16        bf16x8 __attribute__((ext_vector_type(8)));
typedef float         f32x4  __attribute__((ext_vector_type(4)));

#define SEQ  1365
#define SP   1408      // padded seq for q/k/v buffers
#define BHN  128       // B * N_HEADS
#define MTOT 10920     // B * SEQ
#define DIMN 1024
// q pre-scale: 1/sqrt(64) * log2(e)  (softmax done in base 2)
#define QSCALE 0.1803368801111204f

// hardware bf16 conversion (RNE), single VALU op
__device__ __forceinline__ u16 f2bf(float x){
  unsigned r; asm("v_cvt_pk_bf16_f32 %0, %1, %1" : "=v"(r) : "v"(x));
  return (u16)r;
}
__device__ __forceinline__ unsigned cvtpk(float a, float b){
  unsigned r; asm("v_cvt_pk_bf16_f32 %0, %1, %2" : "=v"(r) : "v"(a), "v"(b));
  return r;   // low16 = bf16(a), high16 = bf16(b)
}
__device__ __forceinline__ float bf2f(u16 b){
  return __builtin_bit_cast(float, ((unsigned)b) << 16);
}
__device__ __forceinline__ bf16x8 ldbf8(const u16* p){
  return __builtin_bit_cast(bf16x8, *(const u16x8*)p);
}
__device__ __forceinline__ bf16x8 ldsv(const char* p){
  return __builtin_bit_cast(bf16x8, *(const u16x8*)p);
}
__device__ __forceinline__ f32x4 mfma16(bf16x8 a, bf16x8 b, f32x4 c){
  return __builtin_amdgcn_mfma_f32_16x16x32_bf16(a, b, c, 0, 0, 0);
}
// async global->LDS, 16B per lane; lds dest is wave-uniform base + lane*16
__device__ __forceinline__ void gload16(const u16* g, u16* l){
  __builtin_amdgcn_global_load_lds(
      (const __attribute__((address_space(1))) void*)(g),
      (__attribute__((address_space(3))) void*)(l), 16, 0, 0);
}

// --- transpose fp32 (K,N) -> bf16 (N,K) ------------------------------------
__global__ __launch_bounds__(256) void transpose_bf16(const float* __restrict__ in,
                                                      u16* __restrict__ outT,
                                                      int K, int N){
  __shared__ float tile[32][33];
  const int tx = threadIdx.x & 31, ty = threadIdx.x >> 5;
  const int n0 = blockIdx.x*32, k0 = blockIdx.y*32;
#pragma unroll
  for (int i=0;i<32;i+=8) tile[ty+i][tx] = in[(size_t)(k0+ty+i)*N + n0+tx];
  __syncthreads();
#pragma unroll
  for (int i=0;i<32;i+=8) outT[(size_t)(n0+ty+i)*K + k0+tx] = f2bf(tile[tx][ty+i]);
}

// --- adaLN GEMV -------------------------------------------------------------
__global__ __launch_bounds__(256) void adaln_kernel(const float* __restrict__ cond,
                                                    const float* __restrict__ w,
                                                    const float* __restrict__ bsrc,
                                                    float* __restrict__ wb){
  __shared__ float cs[256];
  const int bt = blockIdx.x >> 3, ch = blockIdx.x & 7;
  const int t = threadIdx.x;
  cs[t] = cond[bt*256 + t];
  __syncthreads();
  const int n = ch*256 + t;
  float acc = bsrc[n];
  for (int j=0;j<256;j++) acc += cs[j] * w[(size_t)j*2048 + n];
  wb[bt*2048 + n] = acc;
}

// --- RoPE cos/sin table: (h, s, c<24) --------------------------------------
__global__ __launch_bounds__(256) void theta_kernel(float* __restrict__ ctab,
                                                    float* __restrict__ stab){
  int idx = blockIdx.x*256 + threadIdx.x;
  if (idx >= 16*SEQ*24) return;
  int c = idx % 24;
  int rest = idx / 24;
  int s = rest % SEQ;
  int h = rest / SEQ;
  float p0 = 0.f, p1 = 0.f, p2 = 0.f;
  if (s >= 1){
    int start, sh; float pr;
    if      (s <   5){start=1;   sh=1; pr=0.2f;}
    else if (s <  21){start=5;   sh=2; pr=0.4f;}
    else if (s <  85){start=21;  sh=3; pr=0.6f;}
    else if (s < 341){start=85;  sh=4; pr=0.8f;}
    else             {start=341; sh=5; pr=1.0f;}
    int n = s - start;
    int row = n >> sh, colp = n & ((1<<sh)-1);
    float g = (float)(1 << sh);
    p0 = -1.f + (2*row+1)/g;
    p1 = -1.f + (2*colp+1)/g;
    p2 = pr;
  }
  int j = c & 7, comp = c >> 3;
  float kf = (float)(j*16 + h);
  float freq = 3.14159265358979323846f * exp2f(kf * (3.3219280948873623f/128.f));
  float pos = (comp==0) ? p0 : ((comp==1) ? p1 : p2);
  float th = pos * freq;
  ctab[idx] = cosf(th);
  stab[idx] = sinf(th);
}

// --- LayerNorm + adaLN scale/shift -> bf16 xn -------------------------------
__global__ __launch_bounds__(256) void ln_kernel(const float* __restrict__ x,
                                                 const float* __restrict__ wb,
                                                 u16* __restrict__ xn){
  const int row = blockIdx.x;
  const int b = row / SEQ;
  const int t = threadIdx.x, w = t>>6, l = t&63;
  const float4 v = ((const float4*)(x + (size_t)row*DIMN))[t];
  float s = v.x + v.y + v.z + v.w;
#pragma unroll
  for (int m=1; m<64; m<<=1) s += __shfl_xor(s, m);
  __shared__ float red1[4], red2[4];
  if (l == 0) red1[w] = s;
  __syncthreads();
  float mean = (red1[0]+red1[1]+red1[2]+red1[3]) * (1.f/1024.f);
  float dx = v.x-mean, dy = v.y-mean, dz = v.z-mean, dw = v.w-mean;
  float q = dx*dx + dy*dy + dz*dz + dw*dw;
#pragma unroll
  for (int m=1; m<64; m<<=1) q += __shfl_xor(q, m);
  if (l == 0) red2[w] = q;
  __syncthreads();
  float var = (red2[0]+red2[1]+red2[2]+red2[3]) * (1.f/1024.f);
  float rs = rsqrtf(var + 1e-5f);
  const float* wrow = wb + b*2048;
  int n0 = t*4;
  u16x4 o;
  o[0] = f2bf(dx*rs*(wrow[n0+0]+1.f) + wrow[1024+n0+0]);
  o[1] = f2bf(dy*rs*(wrow[n0+1]+1.f) + wrow[1024+n0+1]);
  o[2] = f2bf(dz*rs*(wrow[n0+2]+1.f) + wrow[1024+n0+2]);
  o[3] = f2bf(dw*rs*(wrow[n0+3]+1.f) + wrow[1024+n0+3]);
  *(u16x4*)&xn[(size_t)row*DIMN + n0] = o;
}

// ---------------------------------------------------------------------------
// Pipelined GEMM template: BM=BN=128, BK=64, 256 threads, 4 waves (2Mx2N),
// per-wave 64x64 output, acc[4][4].  LDS = 2buf x (128+128)x64x2B = 64 KiB
// -> 2 blocks/CU.  2-deep K-tile prefetch, counted vmcnt(8) (8 gloads/wave
// per K-tile).  Swizzle involution: phys chunk = logical chunk ^ (row&7).
// ---------------------------------------------------------------------------
#define GSTAGE(dstA, dstB, koff)                                   \
  do {                                                             \
    _Pragma("unroll")                                              \
    for (int j_=0;j_<4;j_++) gload16(sA[j_]+(koff), (dstA)+j_*512);\
    _Pragma("unroll")                                              \
    for (int j_=0;j_<4;j_++) gload16(sB[j_]+(koff), (dstB)+j_*512);\
  } while(0)

// --- qkv GEMM: xn(M,K=1024) @ qkv_wT^T(3072,K), scatter q/k/v ---------------
__global__ __launch_bounds__(256, 2) void gemm_qkv(const u16* __restrict__ A,
                                                   const u16* __restrict__ BT,
                                                   const float* __restrict__ bias,
                                                   u16* __restrict__ qb, u16* __restrict__ kb,
                                                   u16* __restrict__ vb){
  __shared__ u16 As[2][8192];   // 128 x 64 per buffer
  __shared__ u16 Bs[2][8192];
  const int t = threadIdx.x, l = t & 63, w = t >> 6;
  const int lr = l & 15, lg = l >> 4;
  const int wr = w >> 1, wc = w & 1;

  // XCD chunking (2064 = 8*258 exact) + 4mt x 24nt supertile order
  const int bid = blockIdx.x;
  const int wg = (bid & 7)*258 + (bid >> 3);
  const int stile = wg/96, rr = wg - stile*96;
  const int mt = stile*4 + rr/24, nt = rr - (rr/24)*24;
  const int bm = mt*128, bn = nt*128;

  // staging sources: per-lane row-in-group + swizzled 16B chunk (involution)
  const int row8 = l >> 3;
  const int gch  = (l & 7) ^ row8;
  const u16* sA[4]; const u16* sB[4];
#pragma unroll
  for (int j=0;j<4;j++){
    int gr = bm + w*32 + j*8 + row8; if (gr >= MTOT) gr = MTOT-1;
    sA[j] = A  + (size_t)gr*1024 + gch*8;
    sB[j] = BT + (size_t)(bn + w*32 + j*8 + row8)*1024 + gch*8;
  }
  u16* dA0 = &As[0][w*2048]; u16* dB0 = &Bs[0][w*2048];
  u16* dA1 = &As[1][w*2048]; u16* dB1 = &Bs[1][w*2048];

  // ds_read fragment byte offsets (swizzle XOR is lane-constant; ^64 = k-sub1)
  const int pch  = (lg ^ (lr & 7)) << 4;
  const int aoff = (wr*64 + lr)*128 + pch;
  const int boff = (wc*64 + lr)*128 + pch;

  f32x4 acc[4][4];
#pragma unroll
  for (int mi=0;mi<4;mi++)
#pragma unroll
    for (int ni=0;ni<4;ni++) acc[mi][ni] = (f32x4){0.f,0.f,0.f,0.f};

  // prologue: stage K-tiles 0,1; wait tile 0 (tile 1 stays in flight)
  GSTAGE(dA0, dB0, 0);
  GSTAGE(dA1, dB1, 64);
  asm volatile("s_waitcnt vmcnt(8)" ::: "memory");
  __builtin_amdgcn_s_barrier();
  __builtin_amdgcn_sched_barrier(0);

  for (int kt = 0; kt < 16; ++kt){
    const int bi = kt & 1;
    const char* Ab = (const char*)As[bi];
    const char* Bb = (const char*)Bs[bi];
    u16* dA = bi ? dA1 : dA0;
    u16* dB = bi ? dB1 : dB0;
    bf16x8 a0[4], b0[4], a1[4], b1[4];
#pragma unroll
    for (int mi=0;mi<4;mi++) a0[mi] = ldsv(Ab + (aoff + mi*2048));
#pragma unroll
    for (int ni=0;ni<4;ni++) b0[ni] = ldsv(Bb + (boff + ni*2048));
#pragma unroll
    for (int mi=0;mi<4;mi++) a1[mi] = ldsv(Ab + ((aoff + mi*2048) ^ 64));
#pragma unroll
    for (int ni=0;ni<4;ni++) b1[ni] = ldsv(Bb + ((boff + ni*2048) ^ 64));
    __builtin_amdgcn_s_setprio(1);
#pragma unroll
    for (int mi=0;mi<4;mi++)
#pragma unroll
      for (int ni=0;ni<4;ni++)
        acc[mi][ni] = mfma16(a0[mi], b0[ni], acc[mi][ni]);
    __builtin_amdgcn_s_setprio(0);
    // all 16 ds_reads landed in regs -> buf[bi] reusable after barrier
    asm volatile("s_waitcnt lgkmcnt(0)" ::: "memory");
    __builtin_amdgcn_s_barrier();
    __builtin_amdgcn_sched_barrier(0);
    if (kt < 14) GSTAGE(dA, dB, (kt+2)*64);
    __builtin_amdgcn_sched_barrier(0);
    __builtin_amdgcn_s_setprio(1);
#pragma unroll
    for (int mi=0;mi<4;mi++)
#pragma unroll
      for (int ni=0;ni<4;ni++)
        acc[mi][ni] = mfma16(a1[mi], b1[ni], acc[mi][ni]);
    __builtin_amdgcn_s_setprio(0);
    if (kt < 15){
      if (kt < 14) asm volatile("s_waitcnt vmcnt(8)" ::: "memory"); // kt+1 landed
      else         asm volatile("s_waitcnt vmcnt(0)" ::: "memory"); // tail drain
      __builtin_amdgcn_s_barrier();
      __builtin_amdgcn_sched_barrier(0);
    }
  }

#pragma unroll
  for (int mi=0;mi<4;mi++)
#pragma unroll
    for (int ni=0;ni<4;ni++){
      int col = bn + wc*64 + ni*16 + lr;    // [0,3072)
      float bia = bias[col];
      int three = col >> 10, rem = col & 1023;
      int h = rem >> 6, d = rem & 63;
      float scl = (three == 0) ? QSCALE : 1.0f;
#pragma unroll
      for (int r=0;r<4;r++){
        int m = bm + wr*64 + mi*16 + lg*4 + r;
        if (m < MTOT){
          int b = m / SEQ; int s = m - b*SEQ;
          u16 val = f2bf((acc[mi][ni][r] + bia) * scl);
          int bh = b*16 + h;
          if (three == 0)      qb[((size_t)bh*SP + s)*64 + d] = val;
          else if (three == 1) kb[((size_t)bh*SP + s)*64 + d] = val;
          else                 vb[((size_t)bh*64 + d)*SP + s] = val;  // V^T layout
        }
      }
    }
}

// --- fused RoPE: one thread per (bh,s) row, rotates q and k (d<48) ----------
__global__ __launch_bounds__(256) void rope2_kernel(u16* __restrict__ qb,
                                                    u16* __restrict__ kb,
                                                    const float* __restrict__ ctab,
                                                    const float* __restrict__ stab){
  int rid = blockIdx.x*256 + threadIdx.x;
  if (rid >= BHN*SEQ) return;
  int bh = rid / SEQ, s = rid - bh*SEQ, h = bh & 15;
  const float* cp = ctab + (size_t)(h*SEQ + s)*24;
  const float* sp = stab + (size_t)(h*SEQ + s)*24;
  float cs[24], sn[24];
#pragma unroll
  for (int i=0;i<6;i++){
    ((float4*)cs)[i] = ((const float4*)cp)[i];
    ((float4*)sn)[i] = ((const float4*)sp)[i];
  }
  size_t base = ((size_t)bh*SP + s)*64;
  u16 buf[48];
#pragma unroll
  for (int i=0;i<6;i++) ((u16x8*)buf)[i] = *(const u16x8*)&qb[base + i*8];
#pragma unroll
  for (int j=0;j<24;j++){
    float x1 = bf2f(buf[j]), x2 = bf2f(buf[24+j]);
    buf[j]    = f2bf(x1*cs[j] - x2*sn[j]);
    buf[24+j] = f2bf(x2*cs[j] + x1*sn[j]);
  }
#pragma unroll
  for (int i=0;i<6;i++) *(u16x8*)&qb[base + i*8] = ((u16x8*)buf)[i];
#pragma unroll
  for (int i=0;i<6;i++) ((u16x8*)buf)[i] = *(const u16x8*)&kb[base + i*8];
#pragma unroll
  for (int j=0;j<24;j++){
    float x1 = bf2f(buf[j]), x2 = bf2f(buf[24+j]);
    buf[j]    = f2bf(x1*cs[j] - x2*sn[j]);
    buf[24+j] = f2bf(x2*cs[j] + x1*sn[j]);
  }
#pragma unroll
  for (int i=0;i<6;i++) *(u16x8*)&kb[base + i*8] = ((u16x8*)buf)[i];
}

// --- flash attention (S^T orientation), fixed-max exp2 softmax --------------
__global__ __launch_bounds__(256) void attn_kernel(const u16* __restrict__ qb,
                                                   const u16* __restrict__ kb,
                                                   const u16* __restrict__ vb,
                                                   u16* __restrict__ ob){
  __shared__ u16 Ks[64*72];    // [key][d]
  __shared__ u16 Vs[64*72];    // [d][key]
  __shared__ u16 Ps[128*72];   // [q][key]
  // long q-tiles (22 k-tiles) first; short ones (6) fill the tail
  const int bx = blockIdx.x;
  const int qt = (bx < 9) ? (bx + 2) : (bx - 9);
  const int bh = blockIdx.y;
  const int t = threadIdx.x, w = t>>6, l = t&63, lr = l&15, lg = l>>4, lg4 = lg<<2;
  const u16* qB = qb + (size_t)bh*SP*64;
  const u16* kB = kb + (size_t)bh*SP*64;
  const u16* vB = vb + (size_t)bh*64*SP;
  const int q0 = qt*128 + w*32;

  bf16x8 qf[2][2];
#pragma unroll
  for (int ni=0; ni<2; ni++)
#pragma unroll
    for (int kk=0; kk<2; kk++)
      qf[ni][kk] = ldbf8(&qB[(size_t)(q0+ni*16+lr)*64 + kk*32 + lg*8]);
  const int qg0 = q0 + lr, qg1 = q0 + 16 + lr;

  f32x4 oacc[2][4];
#pragma unroll
  for (int mo=0;mo<2;mo++)
#pragma unroll
    for (int nd=0;nd<4;nd++) oacc[mo][nd] = (f32x4){0.f,0.f,0.f,0.f};
  float lst[2] = {0.f, 0.f};

  int qmax = min(qt*128+127, SEQ-1);
  int kend = (qmax<1)?1:(qmax<5)?5:(qmax<21)?21:(qmax<85)?85:(qmax<341)?341:SEQ;
  int nkt = (kend + 63) >> 6;

  for (int kt=0; kt<nkt; kt++){
    const int kbase = kt*64;
    __syncthreads();
#pragma unroll
    for (int j=0;j<2;j++){
      int flat = t + j*256;
      int row = flat >> 3, kc = (flat & 7) << 3;
      *(u16x8*)&Ks[row*72+kc] = *(const u16x8*)&kB[(size_t)(kbase+row)*64 + kc];
      *(u16x8*)&Vs[row*72+kc] = *(const u16x8*)&vB[(size_t)row*SP + kbase + kc];
    }
    __syncthreads();

    // S^T = K * Q^T : rows = keys, cols = q
    f32x4 sacc[4][2];
#pragma unroll
    for (int mi=0;mi<4;mi++){
      sacc[mi][0] = (f32x4){0.f,0.f,0.f,0.f};
      sacc[mi][1] = (f32x4){0.f,0.f,0.f,0.f};
    }
#pragma unroll
    for (int mi=0;mi<4;mi++){
      bf16x8 k0f = ldbf8(&Ks[(mi*16+lr)*72 + lg*8]);
      bf16x8 k1f = ldbf8(&Ks[(mi*16+lr)*72 + 32 + lg*8]);
      sacc[mi][0] = mfma16(k0f, qf[0][0], sacc[mi][0]);
      sacc[mi][0] = mfma16(k1f, qf[0][1], sacc[mi][0]);
      sacc[mi][1] = mfma16(k0f, qf[1][0], sacc[mi][1]);
      sacc[mi][1] = mfma16(k1f, qf[1][1], sacc[mi][1]);
    }

    // mask only boundary tiles (wave-uniform branch)
    int lastk = kbase + 63;
    int visLast = (lastk>=SEQ)?(1<<30):(lastk>=341)?341:(lastk>=85)?85:
                  (lastk>=21)?21:(lastk>=5)?5:(lastk>=1)?1:0;
    if (visLast > q0){
#pragma unroll
      for (int mi=0;mi<4;mi++){
        int kv = kbase + mi*16 + lg4;
#pragma unroll
        for (int r=0;r<4;r++){
          int key = kv + r;
          int visv = (key>=SEQ)?(1<<30):(key>=341)?341:(key>=85)?85:
                     (key>=21)?21:(key>=5)?5:(key>=1)?1:0;
          if (qg0 < visv) sacc[mi][0][r] = -1e30f;
          if (qg1 < visv) sacc[mi][1][r] = -1e30f;
        }
      }
    }

    // fixed-max softmax: p = exp2(s) directly (shift-invariant after /l)
    float pa[2] = {0.f, 0.f}, pb[2] = {0.f, 0.f};
#pragma unroll
    for (int mi=0;mi<4;mi++)
#pragma unroll
      for (int ni=0;ni<2;ni++){
        float p0 = __builtin_amdgcn_exp2f(sacc[mi][ni][0]);
        float p1 = __builtin_amdgcn_exp2f(sacc[mi][ni][1]);
        float p2 = __builtin_amdgcn_exp2f(sacc[mi][ni][2]);
        float p3 = __builtin_amdgcn_exp2f(sacc[mi][ni][3]);
        pa[ni] += p0 + p1;
        pb[ni] += p2 + p3;
        uint2 pk = { cvtpk(p0, p1), cvtpk(p2, p3) };
        *(uint2*)&Ps[(w*32+ni*16+lr)*72 + mi*16 + lg4] = pk;  // b64 write
      }
#pragma unroll
    for (int ni=0;ni<2;ni++){
      float s = pa[ni] + pb[ni];
      s += __shfl_xor(s, 16);
      s += __shfl_xor(s, 32);
      lst[ni] += s;
    }

    // PV (Ps rows are wave-private; same-wave DS ordering guarantees RAW)
    bf16x8 pf[2][2];
#pragma unroll
    for (int mo=0;mo<2;mo++)
#pragma unroll
      for (int kk=0;kk<2;kk++)
        pf[mo][kk] = ldbf8(&Ps[(w*32+mo*16+lr)*72 + kk*32 + lg*8]);
#pragma unroll
    for (int nd=0;nd<4;nd++){
      bf16x8 v0 = ldbf8(&Vs[(nd*16+lr)*72 + lg*8]);
      bf16x8 v1 = ldbf8(&Vs[(nd*16+lr)*72 + 32 + lg*8]);
#pragma unroll
      for (int mo=0;mo<2;mo++){
        oacc[mo][nd] = mfma16(pf[mo][0], v0, oacc[mo][nd]);
        oacc[mo][nd] = mfma16(pf[mo][1], v1, oacc[mo][nd]);
      }
    }
  }

  const int b = bh >> 4, h = bh & 15;
  float linv[2][4];
#pragma unroll
  for (int mo=0;mo<2;mo++)
#pragma unroll
    for (int r=0;r<4;r++)
      linv[mo][r] = 1.f / __shfl(lst[mo], lg4 + r);
#pragma unroll
  for (int mo=0;mo<2;mo++)
#pragma unroll
    for (int r=0;r<4;r++){
      int p = q0 + mo*16 + lg4 + r;
      if (p < SEQ){
#pragma unroll
        for (int nd=0;nd<4;nd++)
          ob[((size_t)(b*SEQ + p))*DIMN + h*64 + nd*16 + lr] = f2bf(oacc[mo][nd][r] * linv[mo][r]);
      }
    }
}

// --- out GEMM (pipelined 128x128 template) + bias + fp32 skip ---------------
__global__ __launch_bounds__(256, 2) void gemm_out(const u16* __restrict__ A,
                                                   const u16* __restrict__ BT,
                                                   const float* __restrict__ bias,
                                                   const float* __restrict__ skip,
                                                   float* __restrict__ out){
  __shared__ u16 As[2][8192];
  __shared__ u16 Bs[2][8192];
  const int t = threadIdx.x, l = t & 63, w = t >> 6;
  const int lr = l & 15, lg = l >> 4;
  const int wr = w >> 1, wc = w & 1;

  // XCD chunking (688 = 8*86 exact) + 4mt x 8nt supertile order
  const int bid = blockIdx.x;
  const int wg = (bid & 7)*86 + (bid >> 3);
  const int stile = wg/32, rr = wg - stile*32;
  const int mt = stile*4 + rr/8, nt = rr & 7;
  const int bm = mt*128, bn = nt*128;

  const int row8 = l >> 3;
  const int gch  = (l & 7) ^ row8;
  const u16* sA[4]; const u16* sB[4];
#pragma unroll
  for (int j=0;j<4;j++){
    int gr = bm + w*32 + j*8 + row8; if (gr >= MTOT) gr = MTOT-1;
    sA[j] = A  + (size_t)gr*1024 + gch*8;
    sB[j] = BT + (size_t)(bn + w*32 + j*8 + row8)*1024 + gch*8;
  }
  u16* dA0 = &As[0][w*2048]; u16* dB0 = &Bs[0][w*2048];
  u16* dA1 = &As[1][w*2048]; u16* dB1 = &Bs[1][w*2048];

  const int pch  = (lg ^ (lr & 7)) << 4;
  const int aoff = (wr*64 + lr)*128 + pch;
  const int boff = (wc*64 + lr)*128 + pch;

  f32x4 acc[4][4];
#pragma unroll
  for (int mi=0;mi<4;mi++)
#pragma unroll
    for (int ni=0;ni<4;ni++) acc[mi][ni] = (f32x4){0.f,0.f,0.f,0.f};

  GSTAGE(dA0, dB0, 0);
  GSTAGE(dA1, dB1, 64);
  asm volatile("s_waitcnt vmcnt(8)" ::: "memory");
  __builtin_amdgcn_s_barrier();
  __builtin_amdgcn_sched_barrier(0);

  for (int kt = 0; kt < 16; ++kt){
    const int bi = kt & 1;
    const char* Ab = (const char*)As[bi];
    const char* Bb = (const char*)Bs[bi];
    u16* dA = bi ? dA1 : dA0;
    u16* dB = bi ? dB1 : dB0;
    bf16x8 a0[4], b0[4], a1[4], b1[4];
#pragma unroll
    for (int mi=0;mi<4;mi++) a0[mi] = ldsv(Ab + (aoff + mi*2048));
#pragma unroll
    for (int ni=0;ni<4;ni++) b0[ni] = ldsv(Bb + (boff + ni*2048));
#pragma unroll
    for (int mi=0;mi<4;mi++) a1[mi] = ldsv(Ab + ((aoff + mi*2048) ^ 64));
#pragma unroll
    for (int ni=0;ni<4;ni++) b1[ni] = ldsv(Bb + ((boff + ni*2048) ^ 64));
    __builtin_amdgcn_s_setprio(1);
#pragma unroll
    for (int mi=0;mi<4;mi++)
#pragma unroll
      for (int ni=0;ni<4;ni++)
        acc[mi][ni] = mfma16(a0[mi], b0[ni], acc[mi][ni]);
    __builtin_amdgcn_s_setprio(0);
    asm volatile("s_waitcnt lgkmcnt(0)" ::: "memory");
    __builtin_amdgcn_s_barrier();
    __builtin_amdgcn_sched_barrier(0);
    if (kt < 14) GSTAGE(dA, dB, (kt+2)*64);
    __builtin_amdgcn_sched_barrier(0);
    __builtin_amdgcn_s_setprio(1);
#pragma unroll
    for (int mi=0;mi<4;mi++)
#pragma unroll
      for (int ni=0;ni<4;ni++)
        acc[mi][ni] = mfma16(a1[mi], b1[ni], acc[mi][ni]);
    __builtin_amdgcn_s_setprio(0);
    if (kt < 15){
      if (kt < 14) asm volatile("s_waitcnt vmcnt(8)" ::: "memory");
      else         asm volatile("s_waitcnt vmcnt(0)" ::: "memory");
      __builtin_amdgcn_s_barrier();
      __builtin_amdgcn_sched_barrier(0);
    }
  }

#pragma unroll
  for (int mi=0;mi<4;mi++)
#pragma unroll
    for (int ni=0;ni<4;ni++){
      int col = bn + wc*64 + ni*16 + lr;
      float bia = bias[col];
#pragma unroll
      for (int r=0;r<4;r++){
        int m = bm + wr*64 + mi*16 + lg*4 + r;
        if (m < MTOT){
          size_t idx2 = (size_t)m*DIMN + col;
          out[idx2] = acc[mi][ni][r] + bia + skip[idx2];
        }
      }
    }
}

// ---------------------------------------------------------------------------
extern "C" void kernel_launch(void* const* d_in, const int* in_sizes, int n_in,
                              void* d_out, int out_size, void* d_ws, size_t ws_size,
                              hipStream_t stream) {
  (void)in_sizes; (void)n_in; (void)out_size; (void)ws_size;
  const float* x        = (const float*)d_in[0];
  const float* cond     = (const float*)d_in[1];
  const float* adaln_w  = (const float*)d_in[2];
  const float* adaln_b  = (const float*)d_in[3];
  const float* qkv_w    = (const float*)d_in[4];
  const float* qkv_b    = (const float*)d_in[5];
  const float* out_w    = (const float*)d_in[6];
  const float* out_b    = (const float*)d_in[7];
  float* out = (float*)d_out;

  char* ws = (char*)d_ws;
  size_t off = 0;
  auto alloc = [&](size_t bytes)->void*{
    void* p = ws + off;
    off += (bytes + 255) & ~(size_t)255;
    return p;
  };
  float* wb     = (float*)alloc((size_t)8*2048*4);
  u16*   xn     = (u16*)  alloc((size_t)MTOT*DIMN*2);
  u16*   qkv_wT = (u16*)  alloc((size_t)3072*1024*2);
  u16*   out_wT = (u16*)  alloc((size_t)1024*1024*2);
  u16*   qbuf   = (u16*)  alloc((size_t)BHN*SP*64*2);
  u16*   kbuf   = (u16*)  alloc((size_t)BHN*SP*64*2);
  u16*   vbuf   = (u16*)  alloc((size_t)BHN*SP*64*2);
  float* ctab   = (float*)alloc((size_t)16*SEQ*24*4);
  float* stab   = (float*)alloc((size_t)16*SEQ*24*4);
  u16*   obuf   = xn;   // xn dead after gemm_qkv; reuse for attention output

  transpose_bf16<<<dim3(3072/32, 1024/32), 256, 0, stream>>>(qkv_w, qkv_wT, 1024, 3072);
  transpose_bf16<<<dim3(1024/32, 1024/32), 256, 0, stream>>>(out_w, out_wT, 1024, 1024);
  theta_kernel<<<(16*SEQ*24 + 255)/256, 256, 0, stream>>>(ctab, stab);
  adaln_kernel<<<64, 256, 0, stream>>>(cond, adaln_w, adaln_b, wb);
  ln_kernel<<<MTOT, 256, 0, stream>>>(x, wb, xn);
  // 86 M-tiles (128 rows) x 24 N-tiles (128 cols) = 2064 blocks, 2/CU
  gemm_qkv<<<2064, 256, 0, stream>>>(xn, qkv_wT, qkv_b, qbuf, kbuf, vbuf);
  rope2_kernel<<<(BHN*SEQ + 255)/256, 256, 0, stream>>>(qbuf, kbuf, ctab, stab);
  attn_kernel<<<dim3((SEQ+127)/128, BHN), 256, 0, stream>>>(qbuf, kbuf, vbuf, obuf);
  // 86 M-tiles x 8 N-tiles = 688 blocks, 2/CU
  gemm_out<<<688, 256, 0, stream>>>(obuf, out_wT, out_b, x, out);
}

// Round 3
// 393.827 us; speedup vs baseline: 1.1497x; 1.1497x over previous
//
#include <hip/hip_runtime.h>
#include <math.h>

// ---------------------------------------------------------------------------
// SelfAttention (DiT block): adaLN -> LN -> qkv GEMM -> RoPE -> block-masked
// attention -> out GEMM + skip.  B=8, S=1365, DIM=1024, H=16, D=64.
// R6: epilogue rebuild (the invariant across R3/R4/R5's identical ~135us).
// Old epilogue: 64 scalar 2-byte scattered stores/thread (V^T: 16 lines per
// instr).  New: LDS repack (reuse staging LDS) -> 8x global_store_dwordx4
// per thread, fully coalesced; per-batch m-tiling (11x128 per batch) makes
// all stores 16B-aligned and kills per-element m/SEQ divisions.  K-loop
// (counted-vmcnt 2-deep, T2 swizzle, 2 blocks/CU) untouched from R5.
// ---------------------------------------------------------------------------

typedef unsigned short u16;
typedef unsigned short u16x8 __attribute__((ext_vector_type(8)));
typedef unsigned short u16x4 __attribute__((ext_vector_type(4)));
typedef __bf16        bf16x8 __attribute__((ext_vector_type(8)));
typedef float         f32x4  __attribute__((ext_vector_type(4)));

#define SEQ  1365
#define SP   1408      // padded seq for q/k/v buffers
#define BHN  128       // B * N_HEADS
#define MTOT 10920     // B * SEQ
#define DIMN 1024
// q pre-scale: 1/sqrt(64) * log2(e)  (softmax done in base 2)
#define QSCALE 0.1803368801111204f

// hardware bf16 conversion (RNE), single VALU op
__device__ __forceinline__ u16 f2bf(float x){
  unsigned r; asm("v_cvt_pk_bf16_f32 %0, %1, %1" : "=v"(r) : "v"(x));
  return (u16)r;
}
__device__ __forceinline__ unsigned cvtpk(float a, float b){
  unsigned r; asm("v_cvt_pk_bf16_f32 %0, %1, %2" : "=v"(r) : "v"(a), "v"(b));
  return r;   // low16 = bf16(a), high16 = bf16(b)
}
__device__ __forceinline__ float bf2f(u16 b){
  return __builtin_bit_cast(float, ((unsigned)b) << 16);
}
__device__ __forceinline__ bf16x8 ldbf8(const u16* p){
  return __builtin_bit_cast(bf16x8, *(const u16x8*)p);
}
__device__ __forceinline__ bf16x8 ldsv(const char* p){
  return __builtin_bit_cast(bf16x8, *(const u16x8*)p);
}
__device__ __forceinline__ f32x4 mfma16(bf16x8 a, bf16x8 b, f32x4 c){
  return __builtin_amdgcn_mfma_f32_16x16x32_bf16(a, b, c, 0, 0, 0);
}
// async global->LDS, 16B per lane; lds dest is wave-uniform base + lane*16
__device__ __forceinline__ void gload16(const u16* g, u16* l){
  __builtin_amdgcn_global_load_lds(
      (const __attribute__((address_space(1))) void*)(g),
      (__attribute__((address_space(3))) void*)(l), 16, 0, 0);
}

// --- transpose fp32 (K,N) -> bf16 (N,K) ------------------------------------
__global__ __launch_bounds__(256) void transpose_bf16(const float* __restrict__ in,
                                                      u16* __restrict__ outT,
                                                      int K, int N){
  __shared__ float tile[32][33];
  const int tx = threadIdx.x & 31, ty = threadIdx.x >> 5;
  const int n0 = blockIdx.x*32, k0 = blockIdx.y*32;
#pragma unroll
  for (int i=0;i<32;i+=8) tile[ty+i][tx] = in[(size_t)(k0+ty+i)*N + n0+tx];
  __syncthreads();
#pragma unroll
  for (int i=0;i<32;i+=8) outT[(size_t)(n0+ty+i)*K + k0+tx] = f2bf(tile[tx][ty+i]);
}

// --- adaLN GEMV -------------------------------------------------------------
__global__ __launch_bounds__(256) void adaln_kernel(const float* __restrict__ cond,
                                                    const float* __restrict__ w,
                                                    const float* __restrict__ bsrc,
                                                    float* __restrict__ wb){
  __shared__ float cs[256];
  const int bt = blockIdx.x >> 3, ch = blockIdx.x & 7;
  const int t = threadIdx.x;
  cs[t] = cond[bt*256 + t];
  __syncthreads();
  const int n = ch*256 + t;
  float acc = bsrc[n];
  for (int j=0;j<256;j++) acc += cs[j] * w[(size_t)j*2048 + n];
  wb[bt*2048 + n] = acc;
}

// --- RoPE cos/sin table: (h, s, c<24) --------------------------------------
__global__ __launch_bounds__(256) void theta_kernel(float* __restrict__ ctab,
                                                    float* __restrict__ stab){
  int idx = blockIdx.x*256 + threadIdx.x;
  if (idx >= 16*SEQ*24) return;
  int c = idx % 24;
  int rest = idx / 24;
  int s = rest % SEQ;
  int h = rest / SEQ;
  float p0 = 0.f, p1 = 0.f, p2 = 0.f;
  if (s >= 1){
    int start, sh; float pr;
    if      (s <   5){start=1;   sh=1; pr=0.2f;}
    else if (s <  21){start=5;   sh=2; pr=0.4f;}
    else if (s <  85){start=21;  sh=3; pr=0.6f;}
    else if (s < 341){start=85;  sh=4; pr=0.8f;}
    else             {start=341; sh=5; pr=1.0f;}
    int n = s - start;
    int row = n >> sh, colp = n & ((1<<sh)-1);
    float g = (float)(1 << sh);
    p0 = -1.f + (2*row+1)/g;
    p1 = -1.f + (2*colp+1)/g;
    p2 = pr;
  }
  int j = c & 7, comp = c >> 3;
  float kf = (float)(j*16 + h);
  float freq = 3.14159265358979323846f * exp2f(kf * (3.3219280948873623f/128.f));
  float pos = (comp==0) ? p0 : ((comp==1) ? p1 : p2);
  float th = pos * freq;
  ctab[idx] = cosf(th);
  stab[idx] = sinf(th);
}

// --- LayerNorm + adaLN scale/shift -> bf16 xn -------------------------------
__global__ __launch_bounds__(256) void ln_kernel(const float* __restrict__ x,
                                                 const float* __restrict__ wb,
                                                 u16* __restrict__ xn){
  const int row = blockIdx.x;
  const int b = row / SEQ;
  const int t = threadIdx.x, w = t>>6, l = t&63;
  const float4 v = ((const float4*)(x + (size_t)row*DIMN))[t];
  float s = v.x + v.y + v.z + v.w;
#pragma unroll
  for (int m=1; m<64; m<<=1) s += __shfl_xor(s, m);
  __shared__ float red1[4], red2[4];
  if (l == 0) red1[w] = s;
  __syncthreads();
  float mean = (red1[0]+red1[1]+red1[2]+red1[3]) * (1.f/1024.f);
  float dx = v.x-mean, dy = v.y-mean, dz = v.z-mean, dw = v.w-mean;
  float q = dx*dx + dy*dy + dz*dz + dw*dw;
#pragma unroll
  for (int m=1; m<64; m<<=1) q += __shfl_xor(q, m);
  if (l == 0) red2[w] = q;
  __syncthreads();
  float var = (red2[0]+red2[1]+red2[2]+red2[3]) * (1.f/1024.f);
  float rs = rsqrtf(var + 1e-5f);
  const float* wrow = wb + b*2048;
  int n0 = t*4;
  u16x4 o;
  o[0] = f2bf(dx*rs*(wrow[n0+0]+1.f) + wrow[1024+n0+0]);
  o[1] = f2bf(dy*rs*(wrow[n0+1]+1.f) + wrow[1024+n0+1]);
  o[2] = f2bf(dz*rs*(wrow[n0+2]+1.f) + wrow[1024+n0+2]);
  o[3] = f2bf(dw*rs*(wrow[n0+3]+1.f) + wrow[1024+n0+3]);
  *(u16x4*)&xn[(size_t)row*DIMN + n0] = o;
}

// ---------------------------------------------------------------------------
// Pipelined GEMM template: BM=BN=128, BK=64, 256 threads, 4 waves (2Mx2N),
// per-wave 64x64 output, acc[4][4].  LDS = 64 KiB -> 2 blocks/CU.
// 2-deep K-tile prefetch, counted vmcnt(8).  Per-batch m-tiling: 11 tiles
// of 128 rows per batch (s0 = mtl*128 always 16B-aligned stores).
// ---------------------------------------------------------------------------
#define GSTAGE(dstA, dstB, koff)                                   \
  do {                                                             \
    _Pragma("unroll")                                              \
    for (int j_=0;j_<4;j_++) gload16(sA[j_]+(koff), (dstA)+j_*512);\
    _Pragma("unroll")                                              \
    for (int j_=0;j_<4;j_++) gload16(sB[j_]+(koff), (dstB)+j_*512);\
  } while(0)

// --- qkv GEMM: xn(M,K=1024) @ qkv_wT^T(3072,K), scatter q/k/v ---------------
// q columns pre-scaled by QSCALE (folded out of RoPE; rotation commutes).
__global__ __launch_bounds__(256, 2) void gemm_qkv(const u16* __restrict__ A,
                                                   const u16* __restrict__ BT,
                                                   const float* __restrict__ bias,
                                                   u16* __restrict__ qb, u16* __restrict__ kb,
                                                   u16* __restrict__ vb){
  __shared__ u16 SMEM[32768];      // 64 KiB: staging (2x8KiB A + 2x8KiB B) / repack
  u16* As0 = SMEM;        u16* As1 = SMEM + 8192;
  u16* Bs0 = SMEM + 16384; u16* Bs1 = SMEM + 24576;
  const int t = threadIdx.x, l = t & 63, w = t >> 6;
  const int lr = l & 15, lg = l >> 4;
  const int wr = w >> 1, wc = w & 1;

  // XCD chunking (2112 = 8*264 exact) + 4mt x 24nt supertile order
  const int bid = blockIdx.x;
  const int wg = (bid & 7)*264 + (bid >> 3);
  const int stile = wg/96, rr = wg - stile*96;
  const int mt = stile*4 + rr/24, nt = rr - (rr/24)*24;
  const int bat = mt / 11, mtl = mt - bat*11;     // batch, tile-in-batch
  const int s0 = mtl*128;
  const int bn = nt*128;

  // staging sources: per-lane row-in-group + swizzled 16B chunk (involution)
  const int row8 = l >> 3;
  const int gch  = (l & 7) ^ row8;
  const u16* sA[4]; const u16* sB[4];
#pragma unroll
  for (int j=0;j<4;j++){
    int srow = s0 + w*32 + j*8 + row8; if (srow > SEQ-1) srow = SEQ-1;
    sA[j] = A  + ((size_t)(bat*SEQ + srow))*1024 + gch*8;
    sB[j] = BT + (size_t)(bn + w*32 + j*8 + row8)*1024 + gch*8;
  }
  u16* dA0 = &As0[w*2048]; u16* dB0 = &Bs0[w*2048];
  u16* dA1 = &As1[w*2048]; u16* dB1 = &Bs1[w*2048];

  // ds_read fragment byte offsets (swizzle XOR is lane-constant; ^64 = k-sub1)
  const int pch  = (lg ^ (lr & 7)) << 4;
  const int aoff = (wr*64 + lr)*128 + pch;
  const int boff = (wc*64 + lr)*128 + pch;

  f32x4 acc[4][4];
#pragma unroll
  for (int mi=0;mi<4;mi++)
#pragma unroll
    for (int ni=0;ni<4;ni++) acc[mi][ni] = (f32x4){0.f,0.f,0.f,0.f};

  // prologue: stage K-tiles 0,1; wait tile 0 (tile 1 stays in flight)
  GSTAGE(dA0, dB0, 0);
  GSTAGE(dA1, dB1, 64);
  asm volatile("s_waitcnt vmcnt(8)" ::: "memory");
  __builtin_amdgcn_s_barrier();
  __builtin_amdgcn_sched_barrier(0);

  for (int kt = 0; kt < 16; ++kt){
    const int bi = kt & 1;
    const char* Ab = (const char*)(bi ? As1 : As0);
    const char* Bb = (const char*)(bi ? Bs1 : Bs0);
    u16* dA = bi ? dA1 : dA0;
    u16* dB = bi ? dB1 : dB0;
    bf16x8 a0[4], b0[4], a1[4], b1[4];
#pragma unroll
    for (int mi=0;mi<4;mi++) a0[mi] = ldsv(Ab + (aoff + mi*2048));
#pragma unroll
    for (int ni=0;ni<4;ni++) b0[ni] = ldsv(Bb + (boff + ni*2048));
#pragma unroll
    for (int mi=0;mi<4;mi++) a1[mi] = ldsv(Ab + ((aoff + mi*2048) ^ 64));
#pragma unroll
    for (int ni=0;ni<4;ni++) b1[ni] = ldsv(Bb + ((boff + ni*2048) ^ 64));
    __builtin_amdgcn_s_setprio(1);
#pragma unroll
    for (int mi=0;mi<4;mi++)
#pragma unroll
      for (int ni=0;ni<4;ni++)
        acc[mi][ni] = mfma16(a0[mi], b0[ni], acc[mi][ni]);
    __builtin_amdgcn_s_setprio(0);
    // all 16 ds_reads landed in regs -> buf[bi] reusable after barrier
    asm volatile("s_waitcnt lgkmcnt(0)" ::: "memory");
    __builtin_amdgcn_s_barrier();
    __builtin_amdgcn_sched_barrier(0);
    if (kt < 14) GSTAGE(dA, dB, (kt+2)*64);
    __builtin_amdgcn_sched_barrier(0);
    __builtin_amdgcn_s_setprio(1);
#pragma unroll
    for (int mi=0;mi<4;mi++)
#pragma unroll
      for (int ni=0;ni<4;ni++)
        acc[mi][ni] = mfma16(a1[mi], b1[ni], acc[mi][ni]);
    __builtin_amdgcn_s_setprio(0);
    if (kt < 15){
      if (kt < 14) asm volatile("s_waitcnt vmcnt(8)" ::: "memory"); // kt+1 landed
      else         asm volatile("s_waitcnt vmcnt(0)" ::: "memory"); // tail drain
      __builtin_amdgcn_s_barrier();
      __builtin_amdgcn_sched_barrier(0);
    }
  }

  // ---- epilogue: repack via LDS (stride 136 u16), wide coalesced stores ----
  __syncthreads();                       // all waves done with staging LDS
  const int three = bn >> 10;            // 0:q 1:k 2:v (block-uniform)
  const int hb = (bn & 1023) >> 6;
  if (three < 2){
    // row-major repack: Ls[m_local*136 + col_local]
    const float scl = (three==0) ? QSCALE : 1.0f;
#pragma unroll
    for (int mi=0;mi<4;mi++)
#pragma unroll
      for (int ni=0;ni<4;ni++){
        int col = wc*64 + ni*16 + lr;
        float bia = bias[bn + col];
#pragma unroll
        for (int r=0;r<4;r++){
          int ml = wr*64 + mi*16 + lg*4 + r;
          SMEM[ml*136 + col] = f2bf((acc[mi][ni][r] + bia) * scl);
        }
      }
    __syncthreads();
    u16* dst = (three==0) ? qb : kb;
    const int cs = t & 15, tm = t >> 4;
    const int h = hb + (cs>>3), d8 = (cs&7)*8;
#pragma unroll
    for (int p=0;p<8;p++){
      int ml = p*16 + tm;
      int s = s0 + ml;
      u16x8 vv = *(const u16x8*)&SMEM[ml*136 + cs*8];
      if (s < SEQ)
        *(u16x8*)&dst[((size_t)(bat*16 + h)*SP + s)*64 + d8] = vv;
    }
  } else {
    // col-major repack for V^T: Ls[col_local*136 + m_local], r-pairs as b32
#pragma unroll
    for (int mi=0;mi<4;mi++)
#pragma unroll
      for (int ni=0;ni<4;ni++){
        int col = wc*64 + ni*16 + lr;
        float bia = bias[bn + col];
#pragma unroll
        for (int r=0;r<4;r+=2){
          int ml = wr*64 + mi*16 + lg*4 + r;
          *(unsigned*)&SMEM[col*136 + ml] = cvtpk(acc[mi][ni][r]+bia, acc[mi][ni][r+1]+bia);
        }
      }
    __syncthreads();
    const int ss = t & 15, tdl = t >> 4;
    if (s0 + 127 < SEQ){
#pragma unroll
      for (int p=0;p<8;p++){
        int dl = p*16 + tdl;
        int h = hb + (dl>>6), d = dl & 63;
        u16x8 vv = *(const u16x8*)&SMEM[dl*136 + ss*8];
        *(u16x8*)&vb[((size_t)(bat*16 + h)*64 + d)*SP + s0 + ss*8] = vv;
      }
    } else {
      // tail tile (85 valid rows): guarded scalar stores
#pragma unroll
      for (int p=0;p<8;p++){
        int dl = p*16 + tdl;
        int h = hb + (dl>>6), d = dl & 63;
        size_t rowb = ((size_t)(bat*16 + h)*64 + d)*SP;
#pragma unroll
        for (int j=0;j<8;j++){
          int s = s0 + ss*8 + j;
          if (s < SEQ) vb[rowb + s] = SMEM[dl*136 + ss*8 + j];
        }
      }
    }
  }
}

// --- fused RoPE: one thread per (bh,s) row, rotates q and k (d<48) ----------
__global__ __launch_bounds__(256) void rope2_kernel(u16* __restrict__ qb,
                                                    u16* __restrict__ kb,
                                                    const float* __restrict__ ctab,
                                                    const float* __restrict__ stab){
  int rid = blockIdx.x*256 + threadIdx.x;
  if (rid >= BHN*SEQ) return;
  int bh = rid / SEQ, s = rid - bh*SEQ, h = bh & 15;
  const float* cp = ctab + (size_t)(h*SEQ + s)*24;
  const float* sp = stab + (size_t)(h*SEQ + s)*24;
  float cs[24], sn[24];
#pragma unroll
  for (int i=0;i<6;i++){
    ((float4*)cs)[i] = ((const float4*)cp)[i];
    ((float4*)sn)[i] = ((const float4*)sp)[i];
  }
  size_t base = ((size_t)bh*SP + s)*64;
  u16 buf[48];
#pragma unroll
  for (int i=0;i<6;i++) ((u16x8*)buf)[i] = *(const u16x8*)&qb[base + i*8];
#pragma unroll
  for (int j=0;j<24;j++){
    float x1 = bf2f(buf[j]), x2 = bf2f(buf[24+j]);
    buf[j]    = f2bf(x1*cs[j] - x2*sn[j]);
    buf[24+j] = f2bf(x2*cs[j] + x1*sn[j]);
  }
#pragma unroll
  for (int i=0;i<6;i++) *(u16x8*)&qb[base + i*8] = ((u16x8*)buf)[i];
#pragma unroll
  for (int i=0;i<6;i++) ((u16x8*)buf)[i] = *(const u16x8*)&kb[base + i*8];
#pragma unroll
  for (int j=0;j<24;j++){
    float x1 = bf2f(buf[j]), x2 = bf2f(buf[24+j]);
    buf[j]    = f2bf(x1*cs[j] - x2*sn[j]);
    buf[24+j] = f2bf(x2*cs[j] + x1*sn[j]);
  }
#pragma unroll
  for (int i=0;i<6;i++) *(u16x8*)&kb[base + i*8] = ((u16x8*)buf)[i];
}

// --- flash attention (S^T orientation), fixed-max exp2 softmax --------------
__global__ __launch_bounds__(256) void attn_kernel(const u16* __restrict__ qb,
                                                   const u16* __restrict__ kb,
                                                   const u16* __restrict__ vb,
                                                   u16* __restrict__ ob){
  __shared__ u16 Ks[64*72];    // [key][d]
  __shared__ u16 Vs[64*72];    // [d][key]
  __shared__ u16 Ps[128*72];   // [q][key]
  // long q-tiles (22 k-tiles) first; short ones (6) fill the tail
  const int bx = blockIdx.x;
  const int qt = (bx < 9) ? (bx + 2) : (bx - 9);
  const int bh = blockIdx.y;
  const int t = threadIdx.x, w = t>>6, l = t&63, lr = l&15, lg = l>>4, lg4 = lg<<2;
  const u16* qB = qb + (size_t)bh*SP*64;
  const u16* kB = kb + (size_t)bh*SP*64;
  const u16* vB = vb + (size_t)bh*64*SP;
  const int q0 = qt*128 + w*32;

  bf16x8 qf[2][2];
#pragma unroll
  for (int ni=0; ni<2; ni++)
#pragma unroll
    for (int kk=0; kk<2; kk++)
      qf[ni][kk] = ldbf8(&qB[(size_t)(q0+ni*16+lr)*64 + kk*32 + lg*8]);
  const int qg0 = q0 + lr, qg1 = q0 + 16 + lr;

  f32x4 oacc[2][4];
#pragma unroll
  for (int mo=0;mo<2;mo++)
#pragma unroll
    for (int nd=0;nd<4;nd++) oacc[mo][nd] = (f32x4){0.f,0.f,0.f,0.f};
  float lst[2] = {0.f, 0.f};

  int qmax = min(qt*128+127, SEQ-1);
  int kend = (qmax<1)?1:(qmax<5)?5:(qmax<21)?21:(qmax<85)?85:(qmax<341)?341:SEQ;
  int nkt = (kend + 63) >> 6;

  for (int kt=0; kt<nkt; kt++){
    const int kbase = kt*64;
    __syncthreads();
#pragma unroll
    for (int j=0;j<2;j++){
      int flat = t + j*256;
      int row = flat >> 3, kc = (flat & 7) << 3;
      *(u16x8*)&Ks[row*72+kc] = *(const u16x8*)&kB[(size_t)(kbase+row)*64 + kc];
      *(u16x8*)&Vs[row*72+kc] = *(const u16x8*)&vB[(size_t)row*SP + kbase + kc];
    }
    __syncthreads();

    // S^T = K * Q^T : rows = keys, cols = q
    f32x4 sacc[4][2];
#pragma unroll
    for (int mi=0;mi<4;mi++){
      sacc[mi][0] = (f32x4){0.f,0.f,0.f,0.f};
      sacc[mi][1] = (f32x4){0.f,0.f,0.f,0.f};
    }
#pragma unroll
    for (int mi=0;mi<4;mi++){
      bf16x8 k0f = ldbf8(&Ks[(mi*16+lr)*72 + lg*8]);
      bf16x8 k1f = ldbf8(&Ks[(mi*16+lr)*72 + 32 + lg*8]);
      sacc[mi][0] = mfma16(k0f, qf[0][0], sacc[mi][0]);
      sacc[mi][0] = mfma16(k1f, qf[0][1], sacc[mi][0]);
      sacc[mi][1] = mfma16(k0f, qf[1][0], sacc[mi][1]);
      sacc[mi][1] = mfma16(k1f, qf[1][1], sacc[mi][1]);
    }

    // mask only boundary tiles (wave-uniform branch)
    int lastk = kbase + 63;
    int visLast = (lastk>=SEQ)?(1<<30):(lastk>=341)?341:(lastk>=85)?85:
                  (lastk>=21)?21:(lastk>=5)?5:(lastk>=1)?1:0;
    if (visLast > q0){
#pragma unroll
      for (int mi=0;mi<4;mi++){
        int kv = kbase + mi*16 + lg4;
#pragma unroll
        for (int r=0;r<4;r++){
          int key = kv + r;
          int visv = (key>=SEQ)?(1<<30):(key>=341)?341:(key>=85)?85:
                     (key>=21)?21:(key>=5)?5:(key>=1)?1:0;
          if (qg0 < visv) sacc[mi][0][r] = -1e30f;
          if (qg1 < visv) sacc[mi][1][r] = -1e30f;
        }
      }
    }

    // fixed-max softmax: p = exp2(s) directly (shift-invariant after /l)
    float pa[2] = {0.f, 0.f}, pb[2] = {0.f, 0.f};
#pragma unroll
    for (int mi=0;mi<4;mi++)
#pragma unroll
      for (int ni=0;ni<2;ni++){
        float p0 = __builtin_amdgcn_exp2f(sacc[mi][ni][0]);
        float p1 = __builtin_amdgcn_exp2f(sacc[mi][ni][1]);
        float p2 = __builtin_amdgcn_exp2f(sacc[mi][ni][2]);
        float p3 = __builtin_amdgcn_exp2f(sacc[mi][ni][3]);
        pa[ni] += p0 + p1;
        pb[ni] += p2 + p3;
        uint2 pk = { cvtpk(p0, p1), cvtpk(p2, p3) };
        *(uint2*)&Ps[(w*32+ni*16+lr)*72 + mi*16 + lg4] = pk;  // b64 write
      }
#pragma unroll
    for (int ni=0;ni<2;ni++){
      float s = pa[ni] + pb[ni];
      s += __shfl_xor(s, 16);
      s += __shfl_xor(s, 32);
      lst[ni] += s;
    }

    // PV (Ps rows are wave-private; same-wave DS ordering guarantees RAW)
    bf16x8 pf[2][2];
#pragma unroll
    for (int mo=0;mo<2;mo++)
#pragma unroll
      for (int kk=0;kk<2;kk++)
        pf[mo][kk] = ldbf8(&Ps[(w*32+mo*16+lr)*72 + kk*32 + lg*8]);
#pragma unroll
    for (int nd=0;nd<4;nd++){
      bf16x8 v0 = ldbf8(&Vs[(nd*16+lr)*72 + lg*8]);
      bf16x8 v1 = ldbf8(&Vs[(nd*16+lr)*72 + 32 + lg*8]);
#pragma unroll
      for (int mo=0;mo<2;mo++){
        oacc[mo][nd] = mfma16(pf[mo][0], v0, oacc[mo][nd]);
        oacc[mo][nd] = mfma16(pf[mo][1], v1, oacc[mo][nd]);
      }
    }
  }

  const int b = bh >> 4, h = bh & 15;
  float linv[2][4];
#pragma unroll
  for (int mo=0;mo<2;mo++)
#pragma unroll
    for (int r=0;r<4;r++)
      linv[mo][r] = 1.f / __shfl(lst[mo], lg4 + r);
#pragma unroll
  for (int mo=0;mo<2;mo++)
#pragma unroll
    for (int r=0;r<4;r++){
      int p = q0 + mo*16 + lg4 + r;
      if (p < SEQ){
#pragma unroll
        for (int nd=0;nd<4;nd++)
          ob[((size_t)(b*SEQ + p))*DIMN + h*64 + nd*16 + lr] = f2bf(oacc[mo][nd][r] * linv[mo][r]);
      }
    }
}

// --- out GEMM (pipelined 128x128) + bias + fp32 skip, repack epilogue -------
__global__ __launch_bounds__(256, 2) void gemm_out(const u16* __restrict__ A,
                                                   const u16* __restrict__ BT,
                                                   const float* __restrict__ bias,
                                                   const float* __restrict__ skip,
                                                   float* __restrict__ out){
  __shared__ u16 SMEM[32768];      // 64 KiB
  u16* As0 = SMEM;        u16* As1 = SMEM + 8192;
  u16* Bs0 = SMEM + 16384; u16* Bs1 = SMEM + 24576;
  const int t = threadIdx.x, l = t & 63, w = t >> 6;
  const int lr = l & 15, lg = l >> 4;
  const int wr = w >> 1, wc = w & 1;

  // XCD chunking (704 = 8*88 exact) + 4mt x 8nt supertile order
  const int bid = blockIdx.x;
  const int wg = (bid & 7)*88 + (bid >> 3);
  const int stile = wg/32, rr = wg & 31;
  const int mt = stile*4 + rr/8, nt = rr & 7;
  const int bat = mt / 11, mtl = mt - bat*11;
  const int s0 = mtl*128;
  const int bn = nt*128;

  const int row8 = l >> 3;
  const int gch  = (l & 7) ^ row8;
  const u16* sA[4]; const u16* sB[4];
#pragma unroll
  for (int j=0;j<4;j++){
    int srow = s0 + w*32 + j*8 + row8; if (srow > SEQ-1) srow = SEQ-1;
    sA[j] = A  + ((size_t)(bat*SEQ + srow))*1024 + gch*8;
    sB[j] = BT + (size_t)(bn + w*32 + j*8 + row8)*1024 + gch*8;
  }
  u16* dA0 = &As0[w*2048]; u16* dB0 = &Bs0[w*2048];
  u16* dA1 = &As1[w*2048]; u16* dB1 = &Bs1[w*2048];

  const int pch  = (lg ^ (lr & 7)) << 4;
  const int aoff = (wr*64 + lr)*128 + pch;
  const int boff = (wc*64 + lr)*128 + pch;

  f32x4 acc[4][4];
#pragma unroll
  for (int mi=0;mi<4;mi++)
#pragma unroll
    for (int ni=0;ni<4;ni++) acc[mi][ni] = (f32x4){0.f,0.f,0.f,0.f};

  GSTAGE(dA0, dB0, 0);
  GSTAGE(dA1, dB1, 64);
  asm volatile("s_waitcnt vmcnt(8)" ::: "memory");
  __builtin_amdgcn_s_barrier();
  __builtin_amdgcn_sched_barrier(0);

  for (int kt = 0; kt < 16; ++kt){
    const int bi = kt & 1;
    const char* Ab = (const char*)(bi ? As1 : As0);
    const char* Bb = (const char*)(bi ? Bs1 : Bs0);
    u16* dA = bi ? dA1 : dA0;
    u16* dB = bi ? dB1 : dB0;
    bf16x8 a0[4], b0[4], a1[4], b1[4];
#pragma unroll
    for (int mi=0;mi<4;mi++) a0[mi] = ldsv(Ab + (aoff + mi*2048));
#pragma unroll
    for (int ni=0;ni<4;ni++) b0[ni] = ldsv(Bb + (boff + ni*2048));
#pragma unroll
    for (int mi=0;mi<4;mi++) a1[mi] = ldsv(Ab + ((aoff + mi*2048) ^ 64));
#pragma unroll
    for (int ni=0;ni<4;ni++) b1[ni] = ldsv(Bb + ((boff + ni*2048) ^ 64));
    __builtin_amdgcn_s_setprio(1);
#pragma unroll
    for (int mi=0;mi<4;mi++)
#pragma unroll
      for (int ni=0;ni<4;ni++)
        acc[mi][ni] = mfma16(a0[mi], b0[ni], acc[mi][ni]);
    __builtin_amdgcn_s_setprio(0);
    asm volatile("s_waitcnt lgkmcnt(0)" ::: "memory");
    __builtin_amdgcn_s_barrier();
    __builtin_amdgcn_sched_barrier(0);
    if (kt < 14) GSTAGE(dA, dB, (kt+2)*64);
    __builtin_amdgcn_sched_barrier(0);
    __builtin_amdgcn_s_setprio(1);
#pragma unroll
    for (int mi=0;mi<4;mi++)
#pragma unroll
      for (int ni=0;ni<4;ni++)
        acc[mi][ni] = mfma16(a1[mi], b1[ni], acc[mi][ni]);
    __builtin_amdgcn_s_setprio(0);
    if (kt < 15){
      if (kt < 14) asm volatile("s_waitcnt vmcnt(8)" ::: "memory");
      else         asm volatile("s_waitcnt vmcnt(0)" ::: "memory");
      __builtin_amdgcn_s_barrier();
      __builtin_amdgcn_sched_barrier(0);
    }
  }

  // ---- epilogue: f32 repack (64 KB exact), coalesced skip+store ----
  __syncthreads();
  float* Lf = (float*)SMEM;    // [128][128] f32
#pragma unroll
  for (int mi=0;mi<4;mi++)
#pragma unroll
    for (int ni=0;ni<4;ni++){
      int col = wc*64 + ni*16 + lr;
      float bia = bias[bn + col];
#pragma unroll
      for (int r=0;r<4;r++){
        int ml = wr*64 + mi*16 + lg*4 + r;
        Lf[ml*128 + col] = acc[mi][ni][r] + bia;
      }
    }
  __syncthreads();
  const int cs = t & 31, tm = t >> 5;
#pragma unroll
  for (int p=0;p<16;p++){
    int ml = p*8 + tm;
    int s = s0 + ml;
    if (s < SEQ){
      size_t idx2 = (size_t)(bat*SEQ + s)*1024 + bn + cs*4;
      float4 v4 = *(const float4*)&Lf[ml*128 + cs*4];
      const float4 sk = *(const float4*)&skip[idx2];
      float4 o4; o4.x=v4.x+sk.x; o4.y=v4.y+sk.y; o4.z=v4.z+sk.z; o4.w=v4.w+sk.w;
      *(float4*)&out[idx2] = o4;
    }
  }
}

// ---------------------------------------------------------------------------
extern "C" void kernel_launch(void* const* d_in, const int* in_sizes, int n_in,
                              void* d_out, int out_size, void* d_ws, size_t ws_size,
                              hipStream_t stream) {
  (void)in_sizes; (void)n_in; (void)out_size; (void)ws_size;
  const float* x        = (const float*)d_in[0];
  const float* cond     = (const float*)d_in[1];
  const float* adaln_w  = (const float*)d_in[2];
  const float* adaln_b  = (const float*)d_in[3];
  const float* qkv_w    = (const float*)d_in[4];
  const float* qkv_b    = (const float*)d_in[5];
  const float* out_w    = (const float*)d_in[6];
  const float* out_b    = (const float*)d_in[7];
  float* out = (float*)d_out;

  char* ws = (char*)d_ws;
  size_t off = 0;
  auto alloc = [&](size_t bytes)->void*{
    void* p = ws + off;
    off += (bytes + 255) & ~(size_t)255;
    return p;
  };
  float* wb     = (float*)alloc((size_t)8*2048*4);
  u16*   xn     = (u16*)  alloc((size_t)MTOT*DIMN*2);
  u16*   qkv_wT = (u16*)  alloc((size_t)3072*1024*2);
  u16*   out_wT = (u16*)  alloc((size_t)1024*1024*2);
  u16*   qbuf   = (u16*)  alloc((size_t)BHN*SP*64*2);
  u16*   kbuf   = (u16*)  alloc((size_t)BHN*SP*64*2);
  u16*   vbuf   = (u16*)  alloc((size_t)BHN*SP*64*2);
  float* ctab   = (float*)alloc((size_t)16*SEQ*24*4);
  float* stab   = (float*)alloc((size_t)16*SEQ*24*4);
  u16*   obuf   = xn;   // xn dead after gemm_qkv; reuse for attention output

  transpose_bf16<<<dim3(3072/32, 1024/32), 256, 0, stream>>>(qkv_w, qkv_wT, 1024, 3072);
  transpose_bf16<<<dim3(1024/32, 1024/32), 256, 0, stream>>>(out_w, out_wT, 1024, 1024);
  theta_kernel<<<(16*SEQ*24 + 255)/256, 256, 0, stream>>>(ctab, stab);
  adaln_kernel<<<64, 256, 0, stream>>>(cond, adaln_w, adaln_b, wb);
  ln_kernel<<<MTOT, 256, 0, stream>>>(x, wb, xn);
  // 8 batches x 11 m-tiles x 24 n-tiles = 2112 blocks, 2/CU
  gemm_qkv<<<2112, 256, 0, stream>>>(xn, qkv_wT, qkv_b, qbuf, kbuf, vbuf);
  rope2_kernel<<<(BHN*SEQ + 255)/256, 256, 0, stream>>>(qbuf, kbuf, ctab, stab);
  attn_kernel<<<dim3((SEQ+127)/128, BHN), 256, 0, stream>>>(qbuf, kbuf, vbuf, obuf);
  // 8 x 11 x 8 = 704 blocks, 2/CU
  gemm_out<<<704, 256, 0, stream>>>(obuf, out_wT, out_b, x, out);
}

// Round 4
// 371.050 us; speedup vs baseline: 1.2203x; 1.0614x over previous
//
#include <hip/hip_runtime.h>
#include <math.h>

// ---------------------------------------------------------------------------
// SelfAttention (DiT block): adaLN -> LN -> qkv GEMM -> RoPE -> block-masked
// attention -> out GEMM + skip.  B=8, S=1365, DIM=1024, H=16, D=64.
// R7: attn staging rebuilt on the proven GEMM pipeline: global_load_lds
// direct K/V staging (source-XOR swizzle, unpadded [64][64] tiles), 2-deep
// double-buffered prefetch with counted vmcnt(4) (never drain in-loop),
// LDS 36->50KB total but -18KB vs padded dbuf -> 3 blocks/CU.
// GEMMs unchanged from R6 (repack epilogues fixed the scatter-store wall).
// ---------------------------------------------------------------------------

typedef unsigned short u16;
typedef unsigned short u16x8 __attribute__((ext_vector_type(8)));
typedef unsigned short u16x4 __attribute__((ext_vector_type(4)));
typedef __bf16        bf16x8 __attribute__((ext_vector_type(8)));
typedef float         f32x4  __attribute__((ext_vector_type(4)));

#define SEQ  1365
#define SP   1408      // padded seq for q/k/v buffers
#define BHN  128       // B * N_HEADS
#define MTOT 10920     // B * SEQ
#define DIMN 1024
// q pre-scale: 1/sqrt(64) * log2(e)  (softmax done in base 2)
#define QSCALE 0.1803368801111204f

// hardware bf16 conversion (RNE), single VALU op
__device__ __forceinline__ u16 f2bf(float x){
  unsigned r; asm("v_cvt_pk_bf16_f32 %0, %1, %1" : "=v"(r) : "v"(x));
  return (u16)r;
}
__device__ __forceinline__ unsigned cvtpk(float a, float b){
  unsigned r; asm("v_cvt_pk_bf16_f32 %0, %1, %2" : "=v"(r) : "v"(a), "v"(b));
  return r;   // low16 = bf16(a), high16 = bf16(b)
}
__device__ __forceinline__ float bf2f(u16 b){
  return __builtin_bit_cast(float, ((unsigned)b) << 16);
}
__device__ __forceinline__ bf16x8 ldbf8(const u16* p){
  return __builtin_bit_cast(bf16x8, *(const u16x8*)p);
}
__device__ __forceinline__ bf16x8 ldsv(const char* p){
  return __builtin_bit_cast(bf16x8, *(const u16x8*)p);
}
__device__ __forceinline__ f32x4 mfma16(bf16x8 a, bf16x8 b, f32x4 c){
  return __builtin_amdgcn_mfma_f32_16x16x32_bf16(a, b, c, 0, 0, 0);
}
// async global->LDS, 16B per lane; lds dest is wave-uniform base + lane*16
__device__ __forceinline__ void gload16(const u16* g, u16* l){
  __builtin_amdgcn_global_load_lds(
      (const __attribute__((address_space(1))) void*)(g),
      (__attribute__((address_space(3))) void*)(l), 16, 0, 0);
}

// --- transpose fp32 (K,N) -> bf16 (N,K) ------------------------------------
__global__ __launch_bounds__(256) void transpose_bf16(const float* __restrict__ in,
                                                      u16* __restrict__ outT,
                                                      int K, int N){
  __shared__ float tile[32][33];
  const int tx = threadIdx.x & 31, ty = threadIdx.x >> 5;
  const int n0 = blockIdx.x*32, k0 = blockIdx.y*32;
#pragma unroll
  for (int i=0;i<32;i+=8) tile[ty+i][tx] = in[(size_t)(k0+ty+i)*N + n0+tx];
  __syncthreads();
#pragma unroll
  for (int i=0;i<32;i+=8) outT[(size_t)(n0+ty+i)*K + k0+tx] = f2bf(tile[tx][ty+i]);
}

// --- adaLN GEMV -------------------------------------------------------------
__global__ __launch_bounds__(256) void adaln_kernel(const float* __restrict__ cond,
                                                    const float* __restrict__ w,
                                                    const float* __restrict__ bsrc,
                                                    float* __restrict__ wb){
  __shared__ float cs[256];
  const int bt = blockIdx.x >> 3, ch = blockIdx.x & 7;
  const int t = threadIdx.x;
  cs[t] = cond[bt*256 + t];
  __syncthreads();
  const int n = ch*256 + t;
  float acc = bsrc[n];
  for (int j=0;j<256;j++) acc += cs[j] * w[(size_t)j*2048 + n];
  wb[bt*2048 + n] = acc;
}

// --- RoPE cos/sin table: (h, s, c<24) --------------------------------------
__global__ __launch_bounds__(256) void theta_kernel(float* __restrict__ ctab,
                                                    float* __restrict__ stab){
  int idx = blockIdx.x*256 + threadIdx.x;
  if (idx >= 16*SEQ*24) return;
  int c = idx % 24;
  int rest = idx / 24;
  int s = rest % SEQ;
  int h = rest / SEQ;
  float p0 = 0.f, p1 = 0.f, p2 = 0.f;
  if (s >= 1){
    int start, sh; float pr;
    if      (s <   5){start=1;   sh=1; pr=0.2f;}
    else if (s <  21){start=5;   sh=2; pr=0.4f;}
    else if (s <  85){start=21;  sh=3; pr=0.6f;}
    else if (s < 341){start=85;  sh=4; pr=0.8f;}
    else             {start=341; sh=5; pr=1.0f;}
    int n = s - start;
    int row = n >> sh, colp = n & ((1<<sh)-1);
    float g = (float)(1 << sh);
    p0 = -1.f + (2*row+1)/g;
    p1 = -1.f + (2*colp+1)/g;
    p2 = pr;
  }
  int j = c & 7, comp = c >> 3;
  float kf = (float)(j*16 + h);
  float freq = 3.14159265358979323846f * exp2f(kf * (3.3219280948873623f/128.f));
  float pos = (comp==0) ? p0 : ((comp==1) ? p1 : p2);
  float th = pos * freq;
  ctab[idx] = cosf(th);
  stab[idx] = sinf(th);
}

// --- LayerNorm + adaLN scale/shift -> bf16 xn -------------------------------
__global__ __launch_bounds__(256) void ln_kernel(const float* __restrict__ x,
                                                 const float* __restrict__ wb,
                                                 u16* __restrict__ xn){
  const int row = blockIdx.x;
  const int b = row / SEQ;
  const int t = threadIdx.x, w = t>>6, l = t&63;
  const float4 v = ((const float4*)(x + (size_t)row*DIMN))[t];
  float s = v.x + v.y + v.z + v.w;
#pragma unroll
  for (int m=1; m<64; m<<=1) s += __shfl_xor(s, m);
  __shared__ float red1[4], red2[4];
  if (l == 0) red1[w] = s;
  __syncthreads();
  float mean = (red1[0]+red1[1]+red1[2]+red1[3]) * (1.f/1024.f);
  float dx = v.x-mean, dy = v.y-mean, dz = v.z-mean, dw = v.w-mean;
  float q = dx*dx + dy*dy + dz*dz + dw*dw;
#pragma unroll
  for (int m=1; m<64; m<<=1) q += __shfl_xor(q, m);
  if (l == 0) red2[w] = q;
  __syncthreads();
  float var = (red2[0]+red2[1]+red2[2]+red2[3]) * (1.f/1024.f);
  float rs = rsqrtf(var + 1e-5f);
  const float* wrow = wb + b*2048;
  int n0 = t*4;
  u16x4 o;
  o[0] = f2bf(dx*rs*(wrow[n0+0]+1.f) + wrow[1024+n0+0]);
  o[1] = f2bf(dy*rs*(wrow[n0+1]+1.f) + wrow[1024+n0+1]);
  o[2] = f2bf(dz*rs*(wrow[n0+2]+1.f) + wrow[1024+n0+2]);
  o[3] = f2bf(dw*rs*(wrow[n0+3]+1.f) + wrow[1024+n0+3]);
  *(u16x4*)&xn[(size_t)row*DIMN + n0] = o;
}

// ---------------------------------------------------------------------------
// Pipelined GEMM template: BM=BN=128, BK=64, 256 threads, 4 waves (2Mx2N),
// per-wave 64x64 output, acc[4][4].  LDS = 64 KiB -> 2 blocks/CU.
// 2-deep K-tile prefetch, counted vmcnt(8).  Per-batch m-tiling: 11 tiles
// of 128 rows per batch (s0 = mtl*128 always 16B-aligned stores).
// ---------------------------------------------------------------------------
#define GSTAGE(dstA, dstB, koff)                                   \
  do {                                                             \
    _Pragma("unroll")                                              \
    for (int j_=0;j_<4;j_++) gload16(sA[j_]+(koff), (dstA)+j_*512);\
    _Pragma("unroll")                                              \
    for (int j_=0;j_<4;j_++) gload16(sB[j_]+(koff), (dstB)+j_*512);\
  } while(0)

// --- qkv GEMM: xn(M,K=1024) @ qkv_wT^T(3072,K), scatter q/k/v ---------------
// q columns pre-scaled by QSCALE (folded out of RoPE; rotation commutes).
__global__ __launch_bounds__(256, 2) void gemm_qkv(const u16* __restrict__ A,
                                                   const u16* __restrict__ BT,
                                                   const float* __restrict__ bias,
                                                   u16* __restrict__ qb, u16* __restrict__ kb,
                                                   u16* __restrict__ vb){
  __shared__ u16 SMEM[32768];      // 64 KiB: staging (2x8KiB A + 2x8KiB B) / repack
  u16* As0 = SMEM;        u16* As1 = SMEM + 8192;
  u16* Bs0 = SMEM + 16384; u16* Bs1 = SMEM + 24576;
  const int t = threadIdx.x, l = t & 63, w = t >> 6;
  const int lr = l & 15, lg = l >> 4;
  const int wr = w >> 1, wc = w & 1;

  // XCD chunking (2112 = 8*264 exact) + 4mt x 24nt supertile order
  const int bid = blockIdx.x;
  const int wg = (bid & 7)*264 + (bid >> 3);
  const int stile = wg/96, rr = wg - stile*96;
  const int mt = stile*4 + rr/24, nt = rr - (rr/24)*24;
  const int bat = mt / 11, mtl = mt - bat*11;     // batch, tile-in-batch
  const int s0 = mtl*128;
  const int bn = nt*128;

  // staging sources: per-lane row-in-group + swizzled 16B chunk (involution)
  const int row8 = l >> 3;
  const int gch  = (l & 7) ^ row8;
  const u16* sA[4]; const u16* sB[4];
#pragma unroll
  for (int j=0;j<4;j++){
    int srow = s0 + w*32 + j*8 + row8; if (srow > SEQ-1) srow = SEQ-1;
    sA[j] = A  + ((size_t)(bat*SEQ + srow))*1024 + gch*8;
    sB[j] = BT + (size_t)(bn + w*32 + j*8 + row8)*1024 + gch*8;
  }
  u16* dA0 = &As0[w*2048]; u16* dB0 = &Bs0[w*2048];
  u16* dA1 = &As1[w*2048]; u16* dB1 = &Bs1[w*2048];

  // ds_read fragment byte offsets (swizzle XOR is lane-constant; ^64 = k-sub1)
  const int pch  = (lg ^ (lr & 7)) << 4;
  const int aoff = (wr*64 + lr)*128 + pch;
  const int boff = (wc*64 + lr)*128 + pch;

  f32x4 acc[4][4];
#pragma unroll
  for (int mi=0;mi<4;mi++)
#pragma unroll
    for (int ni=0;ni<4;ni++) acc[mi][ni] = (f32x4){0.f,0.f,0.f,0.f};

  // prologue: stage K-tiles 0,1; wait tile 0 (tile 1 stays in flight)
  GSTAGE(dA0, dB0, 0);
  GSTAGE(dA1, dB1, 64);
  asm volatile("s_waitcnt vmcnt(8)" ::: "memory");
  __builtin_amdgcn_s_barrier();
  __builtin_amdgcn_sched_barrier(0);

  for (int kt = 0; kt < 16; ++kt){
    const int bi = kt & 1;
    const char* Ab = (const char*)(bi ? As1 : As0);
    const char* Bb = (const char*)(bi ? Bs1 : Bs0);
    u16* dA = bi ? dA1 : dA0;
    u16* dB = bi ? dB1 : dB0;
    bf16x8 a0[4], b0[4], a1[4], b1[4];
#pragma unroll
    for (int mi=0;mi<4;mi++) a0[mi] = ldsv(Ab + (aoff + mi*2048));
#pragma unroll
    for (int ni=0;ni<4;ni++) b0[ni] = ldsv(Bb + (boff + ni*2048));
#pragma unroll
    for (int mi=0;mi<4;mi++) a1[mi] = ldsv(Ab + ((aoff + mi*2048) ^ 64));
#pragma unroll
    for (int ni=0;ni<4;ni++) b1[ni] = ldsv(Bb + ((boff + ni*2048) ^ 64));
    __builtin_amdgcn_s_setprio(1);
#pragma unroll
    for (int mi=0;mi<4;mi++)
#pragma unroll
      for (int ni=0;ni<4;ni++)
        acc[mi][ni] = mfma16(a0[mi], b0[ni], acc[mi][ni]);
    __builtin_amdgcn_s_setprio(0);
    // all 16 ds_reads landed in regs -> buf[bi] reusable after barrier
    asm volatile("s_waitcnt lgkmcnt(0)" ::: "memory");
    __builtin_amdgcn_s_barrier();
    __builtin_amdgcn_sched_barrier(0);
    if (kt < 14) GSTAGE(dA, dB, (kt+2)*64);
    __builtin_amdgcn_sched_barrier(0);
    __builtin_amdgcn_s_setprio(1);
#pragma unroll
    for (int mi=0;mi<4;mi++)
#pragma unroll
      for (int ni=0;ni<4;ni++)
        acc[mi][ni] = mfma16(a1[mi], b1[ni], acc[mi][ni]);
    __builtin_amdgcn_s_setprio(0);
    if (kt < 15){
      if (kt < 14) asm volatile("s_waitcnt vmcnt(8)" ::: "memory"); // kt+1 landed
      else         asm volatile("s_waitcnt vmcnt(0)" ::: "memory"); // tail drain
      __builtin_amdgcn_s_barrier();
      __builtin_amdgcn_sched_barrier(0);
    }
  }

  // ---- epilogue: repack via LDS (stride 136 u16), wide coalesced stores ----
  __syncthreads();                       // all waves done with staging LDS
  const int three = bn >> 10;            // 0:q 1:k 2:v (block-uniform)
  const int hb = (bn & 1023) >> 6;
  if (three < 2){
    // row-major repack: Ls[m_local*136 + col_local]
    const float scl = (three==0) ? QSCALE : 1.0f;
#pragma unroll
    for (int mi=0;mi<4;mi++)
#pragma unroll
      for (int ni=0;ni<4;ni++){
        int col = wc*64 + ni*16 + lr;
        float bia = bias[bn + col];
#pragma unroll
        for (int r=0;r<4;r++){
          int ml = wr*64 + mi*16 + lg*4 + r;
          SMEM[ml*136 + col] = f2bf((acc[mi][ni][r] + bia) * scl);
        }
      }
    __syncthreads();
    u16* dst = (three==0) ? qb : kb;
    const int cs = t & 15, tm = t >> 4;
    const int h = hb + (cs>>3), d8 = (cs&7)*8;
#pragma unroll
    for (int p=0;p<8;p++){
      int ml = p*16 + tm;
      int s = s0 + ml;
      u16x8 vv = *(const u16x8*)&SMEM[ml*136 + cs*8];
      if (s < SEQ)
        *(u16x8*)&dst[((size_t)(bat*16 + h)*SP + s)*64 + d8] = vv;
    }
  } else {
    // col-major repack for V^T: Ls[col_local*136 + m_local], r-pairs as b32
#pragma unroll
    for (int mi=0;mi<4;mi++)
#pragma unroll
      for (int ni=0;ni<4;ni++){
        int col = wc*64 + ni*16 + lr;
        float bia = bias[bn + col];
#pragma unroll
        for (int r=0;r<4;r+=2){
          int ml = wr*64 + mi*16 + lg*4 + r;
          *(unsigned*)&SMEM[col*136 + ml] = cvtpk(acc[mi][ni][r]+bia, acc[mi][ni][r+1]+bia);
        }
      }
    __syncthreads();
    const int ss = t & 15, tdl = t >> 4;
    if (s0 + 127 < SEQ){
#pragma unroll
      for (int p=0;p<8;p++){
        int dl = p*16 + tdl;
        int h = hb + (dl>>6), d = dl & 63;
        u16x8 vv = *(const u16x8*)&SMEM[dl*136 + ss*8];
        *(u16x8*)&vb[((size_t)(bat*16 + h)*64 + d)*SP + s0 + ss*8] = vv;
      }
    } else {
      // tail tile (85 valid rows): guarded scalar stores
#pragma unroll
      for (int p=0;p<8;p++){
        int dl = p*16 + tdl;
        int h = hb + (dl>>6), d = dl & 63;
        size_t rowb = ((size_t)(bat*16 + h)*64 + d)*SP;
#pragma unroll
        for (int j=0;j<8;j++){
          int s = s0 + ss*8 + j;
          if (s < SEQ) vb[rowb + s] = SMEM[dl*136 + ss*8 + j];
        }
      }
    }
  }
}

// --- fused RoPE: one thread per (bh,s) row, rotates q and k (d<48) ----------
__global__ __launch_bounds__(256) void rope2_kernel(u16* __restrict__ qb,
                                                    u16* __restrict__ kb,
                                                    const float* __restrict__ ctab,
                                                    const float* __restrict__ stab){
  int rid = blockIdx.x*256 + threadIdx.x;
  if (rid >= BHN*SEQ) return;
  int bh = rid / SEQ, s = rid - bh*SEQ, h = bh & 15;
  const float* cp = ctab + (size_t)(h*SEQ + s)*24;
  const float* sp = stab + (size_t)(h*SEQ + s)*24;
  float cs[24], sn[24];
#pragma unroll
  for (int i=0;i<6;i++){
    ((float4*)cs)[i] = ((const float4*)cp)[i];
    ((float4*)sn)[i] = ((const float4*)sp)[i];
  }
  size_t base = ((size_t)bh*SP + s)*64;
  u16 buf[48];
#pragma unroll
  for (int i=0;i<6;i++) ((u16x8*)buf)[i] = *(const u16x8*)&qb[base + i*8];
#pragma unroll
  for (int j=0;j<24;j++){
    float x1 = bf2f(buf[j]), x2 = bf2f(buf[24+j]);
    buf[j]    = f2bf(x1*cs[j] - x2*sn[j]);
    buf[24+j] = f2bf(x2*cs[j] + x1*sn[j]);
  }
#pragma unroll
  for (int i=0;i<6;i++) *(u16x8*)&qb[base + i*8] = ((u16x8*)buf)[i];
#pragma unroll
  for (int i=0;i<6;i++) ((u16x8*)buf)[i] = *(const u16x8*)&kb[base + i*8];
#pragma unroll
  for (int j=0;j<24;j++){
    float x1 = bf2f(buf[j]), x2 = bf2f(buf[24+j]);
    buf[j]    = f2bf(x1*cs[j] - x2*sn[j]);
    buf[24+j] = f2bf(x2*cs[j] + x1*sn[j]);
  }
#pragma unroll
  for (int i=0;i<6;i++) *(u16x8*)&kb[base + i*8] = ((u16x8*)buf)[i];
}

// --- flash attention (S^T orientation), fixed-max exp2 softmax --------------
// R7: K/V staged via global_load_lds (source-XOR swizzle, unpadded [64][64]),
// double-buffered 2-deep prefetch, counted vmcnt(4).  50 KB LDS -> 3 blk/CU.
__global__ __launch_bounds__(256, 3) void attn_kernel(const u16* __restrict__ qb,
                                                      const u16* __restrict__ kb,
                                                      const u16* __restrict__ vb,
                                                      u16* __restrict__ ob){
  __shared__ u16 Ks[2][4096];   // [buf][key][d]  64x64, swizzled chunks
  __shared__ u16 Vs[2][4096];   // [buf][d][key]  64x64, swizzled chunks
  __shared__ u16 Ps[128*72];    // [q][key] padded
  // long q-tiles (22 k-tiles) first; short ones (6) fill the tail
  const int bx = blockIdx.x;
  const int qt = (bx < 9) ? (bx + 2) : (bx - 9);
  const int bh = blockIdx.y;
  const int t = threadIdx.x, w = t>>6, l = t&63, lr = l&15, lg = l>>4, lg4 = lg<<2;
  const u16* qB = qb + (size_t)bh*SP*64;
  const u16* kB = kb + (size_t)bh*SP*64;
  const u16* vB = vb + (size_t)bh*64*SP;
  const int q0 = qt*128 + w*32;

  bf16x8 qf[2][2];
#pragma unroll
  for (int ni=0; ni<2; ni++)
#pragma unroll
    for (int kk=0; kk<2; kk++)
      qf[ni][kk] = ldbf8(&qB[(size_t)(q0+ni*16+lr)*64 + kk*32 + lg*8]);
  const int qg0 = q0 + lr, qg1 = q0 + 16 + lr;

  // staging source pointers (per-lane, swizzled chunk involution)
  const int row8 = l >> 3;
  const int gch  = (l & 7) ^ row8;
  const u16* sK[2]; const u16* sV[2];
#pragma unroll
  for (int j=0;j<2;j++){
    sK[j] = kB + (size_t)(w*16 + j*8 + row8)*64 + gch*8;   // + kbase*64 at issue
    sV[j] = vB + (size_t)(w*16 + j*8 + row8)*SP + gch*8;   // + kbase at issue
  }
  // swizzled read byte-offsets (lane-constant)
  const int sw0 = ((lg)   ^ (lr & 7)) << 4;   // chunks 0..3
  const int sw1 = ((4+lg) ^ (lr & 7)) << 4;   // chunks 4..7

#define KVSTAGE(buf_, kb_)                                          \
  do {                                                              \
    _Pragma("unroll")                                               \
    for (int j_=0;j_<2;j_++){                                       \
      gload16(sK[j_] + (kb_)*64, &Ks[buf_][(w*16+j_*8)*64]);        \
      gload16(sV[j_] + (kb_),    &Vs[buf_][(w*16+j_*8)*64]);        \
    }                                                               \
  } while(0)

  f32x4 oacc[2][4];
#pragma unroll
  for (int mo=0;mo<2;mo++)
#pragma unroll
    for (int nd=0;nd<4;nd++) oacc[mo][nd] = (f32x4){0.f,0.f,0.f,0.f};
  float lst[2] = {0.f, 0.f};

  int qmax = min(qt*128+127, SEQ-1);
  int kend = (qmax<1)?1:(qmax<5)?5:(qmax<21)?21:(qmax<85)?85:(qmax<341)?341:SEQ;
  int nkt = (kend + 63) >> 6;    // always >= 6

  // prologue: stage tiles 0 and 1 (4 gloads/wave each)
  KVSTAGE(0, 0);
  KVSTAGE(1, 64);

  for (int kt=0; kt<nkt; kt++){
    const int kbase = kt*64;
    const int cur = kt & 1;
    // tile kt landed when only tile kt+1's 4 loads remain outstanding
    asm volatile("s_waitcnt vmcnt(4)" ::: "memory");
    __builtin_amdgcn_s_barrier();
    __builtin_amdgcn_sched_barrier(0);
    const char* Kb = (const char*)&Ks[cur][0];
    const char* Vb = (const char*)&Vs[cur][0];

    // S^T = K * Q^T : rows = keys, cols = q
    f32x4 sacc[4][2];
#pragma unroll
    for (int mi=0;mi<4;mi++){
      sacc[mi][0] = (f32x4){0.f,0.f,0.f,0.f};
      sacc[mi][1] = (f32x4){0.f,0.f,0.f,0.f};
    }
#pragma unroll
    for (int mi=0;mi<4;mi++){
      bf16x8 k0f = ldsv(Kb + (mi*16+lr)*128 + sw0);
      bf16x8 k1f = ldsv(Kb + (mi*16+lr)*128 + sw1);
      sacc[mi][0] = mfma16(k0f, qf[0][0], sacc[mi][0]);
      sacc[mi][0] = mfma16(k1f, qf[0][1], sacc[mi][0]);
      sacc[mi][1] = mfma16(k0f, qf[1][0], sacc[mi][1]);
      sacc[mi][1] = mfma16(k1f, qf[1][1], sacc[mi][1]);
    }

    // mask only boundary tiles (wave-uniform branch)
    int lastk = kbase + 63;
    int visLast = (lastk>=SEQ)?(1<<30):(lastk>=341)?341:(lastk>=85)?85:
                  (lastk>=21)?21:(lastk>=5)?5:(lastk>=1)?1:0;
    if (visLast > q0){
#pragma unroll
      for (int mi=0;mi<4;mi++){
        int kv = kbase + mi*16 + lg4;
#pragma unroll
        for (int r=0;r<4;r++){
          int key = kv + r;
          int visv = (key>=SEQ)?(1<<30):(key>=341)?341:(key>=85)?85:
                     (key>=21)?21:(key>=5)?5:(key>=1)?1:0;
          if (qg0 < visv) sacc[mi][0][r] = -1e30f;
          if (qg1 < visv) sacc[mi][1][r] = -1e30f;
        }
      }
    }

    // fixed-max softmax: p = exp2(s) directly (shift-invariant after /l)
    float pa[2] = {0.f, 0.f}, pb[2] = {0.f, 0.f};
#pragma unroll
    for (int mi=0;mi<4;mi++)
#pragma unroll
      for (int ni=0;ni<2;ni++){
        float p0 = __builtin_amdgcn_exp2f(sacc[mi][ni][0]);
        float p1 = __builtin_amdgcn_exp2f(sacc[mi][ni][1]);
        float p2 = __builtin_amdgcn_exp2f(sacc[mi][ni][2]);
        float p3 = __builtin_amdgcn_exp2f(sacc[mi][ni][3]);
        pa[ni] += p0 + p1;
        pb[ni] += p2 + p3;
        uint2 pk = { cvtpk(p0, p1), cvtpk(p2, p3) };
        *(uint2*)&Ps[(w*32+ni*16+lr)*72 + mi*16 + lg4] = pk;  // b64 write
      }
#pragma unroll
    for (int ni=0;ni<2;ni++){
      float s = pa[ni] + pb[ni];
      s += __shfl_xor(s, 16);
      s += __shfl_xor(s, 32);
      lst[ni] += s;
    }

    // PV (Ps rows are wave-private; same-wave DS ordering guarantees RAW)
    bf16x8 pf[2][2];
#pragma unroll
    for (int mo=0;mo<2;mo++)
#pragma unroll
      for (int kk=0;kk<2;kk++)
        pf[mo][kk] = ldbf8(&Ps[(w*32+mo*16+lr)*72 + kk*32 + lg*8]);
#pragma unroll
    for (int nd=0;nd<4;nd++){
      bf16x8 v0 = ldsv(Vb + (nd*16+lr)*128 + sw0);
      bf16x8 v1 = ldsv(Vb + (nd*16+lr)*128 + sw1);
#pragma unroll
      for (int mo=0;mo<2;mo++){
        oacc[mo][nd] = mfma16(pf[mo][0], v0, oacc[mo][nd]);
        oacc[mo][nd] = mfma16(pf[mo][1], v1, oacc[mo][nd]);
      }
    }

    // all LDS reads done -> buf[cur] reusable; prefetch tile kt+2 into it
    asm volatile("s_waitcnt lgkmcnt(0)" ::: "memory");
    __builtin_amdgcn_s_barrier();
    __builtin_amdgcn_sched_barrier(0);
    if (kt < nkt-1){
      int kpf = (kt+2 < nkt ? kt+2 : nkt-1)*64;   // clamp keeps vmcnt uniform
      KVSTAGE(cur, kpf);
    }
    __builtin_amdgcn_sched_barrier(0);
  }

  const int b = bh >> 4, h = bh & 15;
  float linv[2][4];
#pragma unroll
  for (int mo=0;mo<2;mo++)
#pragma unroll
    for (int r=0;r<4;r++)
      linv[mo][r] = 1.f / __shfl(lst[mo], lg4 + r);
#pragma unroll
  for (int mo=0;mo<2;mo++)
#pragma unroll
    for (int r=0;r<4;r++){
      int p = q0 + mo*16 + lg4 + r;
      if (p < SEQ){
#pragma unroll
        for (int nd=0;nd<4;nd++)
          ob[((size_t)(b*SEQ + p))*DIMN + h*64 + nd*16 + lr] = f2bf(oacc[mo][nd][r] * linv[mo][r]);
      }
    }
#undef KVSTAGE
}

// --- out GEMM (pipelined 128x128) + bias + fp32 skip, repack epilogue -------
__global__ __launch_bounds__(256, 2) void gemm_out(const u16* __restrict__ A,
                                                   const u16* __restrict__ BT,
                                                   const float* __restrict__ bias,
                                                   const float* __restrict__ skip,
                                                   float* __restrict__ out){
  __shared__ u16 SMEM[32768];      // 64 KiB
  u16* As0 = SMEM;        u16* As1 = SMEM + 8192;
  u16* Bs0 = SMEM + 16384; u16* Bs1 = SMEM + 24576;
  const int t = threadIdx.x, l = t & 63, w = t >> 6;
  const int lr = l & 15, lg = l >> 4;
  const int wr = w >> 1, wc = w & 1;

  // XCD chunking (704 = 8*88 exact) + 4mt x 8nt supertile order
  const int bid = blockIdx.x;
  const int wg = (bid & 7)*88 + (bid >> 3);
  const int stile = wg/32, rr = wg & 31;
  const int mt = stile*4 + rr/8, nt = rr & 7;
  const int bat = mt / 11, mtl = mt - bat*11;
  const int s0 = mtl*128;
  const int bn = nt*128;

  const int row8 = l >> 3;
  const int gch  = (l & 7) ^ row8;
  const u16* sA[4]; const u16* sB[4];
#pragma unroll
  for (int j=0;j<4;j++){
    int srow = s0 + w*32 + j*8 + row8; if (srow > SEQ-1) srow = SEQ-1;
    sA[j] = A  + ((size_t)(bat*SEQ + srow))*1024 + gch*8;
    sB[j] = BT + (size_t)(bn + w*32 + j*8 + row8)*1024 + gch*8;
  }
  u16* dA0 = &As0[w*2048]; u16* dB0 = &Bs0[w*2048];
  u16* dA1 = &As1[w*2048]; u16* dB1 = &Bs1[w*2048];

  const int pch  = (lg ^ (lr & 7)) << 4;
  const int aoff = (wr*64 + lr)*128 + pch;
  const int boff = (wc*64 + lr)*128 + pch;

  f32x4 acc[4][4];
#pragma unroll
  for (int mi=0;mi<4;mi++)
#pragma unroll
    for (int ni=0;ni<4;ni++) acc[mi][ni] = (f32x4){0.f,0.f,0.f,0.f};

  GSTAGE(dA0, dB0, 0);
  GSTAGE(dA1, dB1, 64);
  asm volatile("s_waitcnt vmcnt(8)" ::: "memory");
  __builtin_amdgcn_s_barrier();
  __builtin_amdgcn_sched_barrier(0);

  for (int kt = 0; kt < 16; ++kt){
    const int bi = kt & 1;
    const char* Ab = (const char*)(bi ? As1 : As0);
    const char* Bb = (const char*)(bi ? Bs1 : Bs0);
    u16* dA = bi ? dA1 : dA0;
    u16* dB = bi ? dB1 : dB0;
    bf16x8 a0[4], b0[4], a1[4], b1[4];
#pragma unroll
    for (int mi=0;mi<4;mi++) a0[mi] = ldsv(Ab + (aoff + mi*2048));
#pragma unroll
    for (int ni=0;ni<4;ni++) b0[ni] = ldsv(Bb + (boff + ni*2048));
#pragma unroll
    for (int mi=0;mi<4;mi++) a1[mi] = ldsv(Ab + ((aoff + mi*2048) ^ 64));
#pragma unroll
    for (int ni=0;ni<4;ni++) b1[ni] = ldsv(Bb + ((boff + ni*2048) ^ 64));
    __builtin_amdgcn_s_setprio(1);
#pragma unroll
    for (int mi=0;mi<4;mi++)
#pragma unroll
      for (int ni=0;ni<4;ni++)
        acc[mi][ni] = mfma16(a0[mi], b0[ni], acc[mi][ni]);
    __builtin_amdgcn_s_setprio(0);
    asm volatile("s_waitcnt lgkmcnt(0)" ::: "memory");
    __builtin_amdgcn_s_barrier();
    __builtin_amdgcn_sched_barrier(0);
    if (kt < 14) GSTAGE(dA, dB, (kt+2)*64);
    __builtin_amdgcn_sched_barrier(0);
    __builtin_amdgcn_s_setprio(1);
#pragma unroll
    for (int mi=0;mi<4;mi++)
#pragma unroll
      for (int ni=0;ni<4;ni++)
        acc[mi][ni] = mfma16(a1[mi], b1[ni], acc[mi][ni]);
    __builtin_amdgcn_s_setprio(0);
    if (kt < 15){
      if (kt < 14) asm volatile("s_waitcnt vmcnt(8)" ::: "memory");
      else         asm volatile("s_waitcnt vmcnt(0)" ::: "memory");
      __builtin_amdgcn_s_barrier();
      __builtin_amdgcn_sched_barrier(0);
    }
  }

  // ---- epilogue: f32 repack (64 KB exact), coalesced skip+store ----
  __syncthreads();
  float* Lf = (float*)SMEM;    // [128][128] f32
#pragma unroll
  for (int mi=0;mi<4;mi++)
#pragma unroll
    for (int ni=0;ni<4;ni++){
      int col = wc*64 + ni*16 + lr;
      float bia = bias[bn + col];
#pragma unroll
      for (int r=0;r<4;r++){
        int ml = wr*64 + mi*16 + lg*4 + r;
        Lf[ml*128 + col] = acc[mi][ni][r] + bia;
      }
    }
  __syncthreads();
  const int cs = t & 31, tm = t >> 5;
#pragma unroll
  for (int p=0;p<16;p++){
    int ml = p*8 + tm;
    int s = s0 + ml;
    if (s < SEQ){
      size_t idx2 = (size_t)(bat*SEQ + s)*1024 + bn + cs*4;
      float4 v4 = *(const float4*)&Lf[ml*128 + cs*4];
      const float4 sk = *(const float4*)&skip[idx2];
      float4 o4; o4.x=v4.x+sk.x; o4.y=v4.y+sk.y; o4.z=v4.z+sk.z; o4.w=v4.w+sk.w;
      *(float4*)&out[idx2] = o4;
    }
  }
}

// ---------------------------------------------------------------------------
extern "C" void kernel_launch(void* const* d_in, const int* in_sizes, int n_in,
                              void* d_out, int out_size, void* d_ws, size_t ws_size,
                              hipStream_t stream) {
  (void)in_sizes; (void)n_in; (void)out_size; (void)ws_size;
  const float* x        = (const float*)d_in[0];
  const float* cond     = (const float*)d_in[1];
  const float* adaln_w  = (const float*)d_in[2];
  const float* adaln_b  = (const float*)d_in[3];
  const float* qkv_w    = (const float*)d_in[4];
  const float* qkv_b    = (const float*)d_in[5];
  const float* out_w    = (const float*)d_in[6];
  const float* out_b    = (const float*)d_in[7];
  float* out = (float*)d_out;

  char* ws = (char*)d_ws;
  size_t off = 0;
  auto alloc = [&](size_t bytes)->void*{
    void* p = ws + off;
    off += (bytes + 255) & ~(size_t)255;
    return p;
  };
  float* wb     = (float*)alloc((size_t)8*2048*4);
  u16*   xn     = (u16*)  alloc((size_t)MTOT*DIMN*2);
  u16*   qkv_wT = (u16*)  alloc((size_t)3072*1024*2);
  u16*   out_wT = (u16*)  alloc((size_t)1024*1024*2);
  u16*   qbuf   = (u16*)  alloc((size_t)BHN*SP*64*2);
  u16*   kbuf   = (u16*)  alloc((size_t)BHN*SP*64*2);
  u16*   vbuf   = (u16*)  alloc((size_t)BHN*SP*64*2);
  float* ctab   = (float*)alloc((size_t)16*SEQ*24*4);
  float* stab   = (float*)alloc((size_t)16*SEQ*24*4);
  u16*   obuf   = xn;   // xn dead after gemm_qkv; reuse for attention output

  transpose_bf16<<<dim3(3072/32, 1024/32), 256, 0, stream>>>(qkv_w, qkv_wT, 1024, 3072);
  transpose_bf16<<<dim3(1024/32, 1024/32), 256, 0, stream>>>(out_w, out_wT, 1024, 1024);
  theta_kernel<<<(16*SEQ*24 + 255)/256, 256, 0, stream>>>(ctab, stab);
  adaln_kernel<<<64, 256, 0, stream>>>(cond, adaln_w, adaln_b, wb);
  ln_kernel<<<MTOT, 256, 0, stream>>>(x, wb, xn);
  // 8 batches x 11 m-tiles x 24 n-tiles = 2112 blocks, 2/CU
  gemm_qkv<<<2112, 256, 0, stream>>>(xn, qkv_wT, qkv_b, qbuf, kbuf, vbuf);
  rope2_kernel<<<(BHN*SEQ + 255)/256, 256, 0, stream>>>(qbuf, kbuf, ctab, stab);
  attn_kernel<<<dim3((SEQ+127)/128, BHN), 256, 0, stream>>>(qbuf, kbuf, vbuf, obuf);
  // 8 x 11 x 8 = 704 blocks, 2/CU
  gemm_out<<<704, 256, 0, stream>>>(obuf, out_wT, out_b, x, out);
}